// Round 9
// baseline (1170.288 us; speedup 1.0000x reference)
//
#include <hip/hip_runtime.h>
#include <math.h>

#define HID 64
#define INC 256
#define LN_EPS 1e-5f
#define ALPHA 0.1f
#define NBKT 256     // max buckets (N<=131072); actual = ceil(N/512)
#define BCAP 12288   // per-bucket capacity; E/N*512 = 8192 expected, +45 sigma margin

typedef unsigned short ushort_t;
typedef unsigned int uint_t;
using short8v = __attribute__((ext_vector_type(8))) short;
using float4v = __attribute__((ext_vector_type(4))) float;

__device__ __forceinline__ float gelu_exact(float x) {
    return 0.5f * x * (1.0f + erff(x * 0.70710678118654752f));
}

__device__ __forceinline__ ushort_t f2bf(float f) {
    uint_t u = __float_as_uint(f);
    return (ushort_t)((u + 0x7fffu + ((u >> 16) & 1u)) >> 16);
}
__device__ __forceinline__ float bf_lo(uint_t v) { return __uint_as_float(v << 16); }
__device__ __forceinline__ float bf_hi(uint_t v) { return __uint_as_float(v & 0xffff0000u); }

__device__ __forceinline__ void split_bf(float f, ushort_t& hi, ushort_t& lo) {
    uint_t ub = __float_as_uint(f);
    uint_t h = (ub + 0x7fffu + ((ub >> 16) & 1u)) >> 16;
    hi = (ushort_t)h;
    float fl = f - __uint_as_float(h << 16);
    uint_t lb = __float_as_uint(fl);
    lo = (ushort_t)((lb + 0x7fffu + ((lb >> 16) & 1u)) >> 16);
}

// ---------- prep: W1 [256][64] f32 -> swizzled W^T bf16 hi/lo [64][256] ----------
__global__ __launch_bounds__(256) void k_prepW(const float* __restrict__ W1,
                                               ushort_t* __restrict__ whi,
                                               ushort_t* __restrict__ wlo) {
    int e = blockIdx.x * 256 + threadIdx.x;  // 16384 total
    int col = e & 63, k = e >> 6;
    float f = W1[(size_t)k * HID + col];
    ushort_t hi, lo;
    split_bf(f, hi, lo);
    int idx = col * 256 + (((k >> 3) ^ (col & 7)) << 3) + (k & 7);
    whi[idx] = hi;
    wlo[idx] = lo;
}

// ---------- prep: W2 [64][64] f32 -> swizzled W^T bf16 hi/lo [64][64] ----------
__global__ __launch_bounds__(256) void k_prepW2(const float* __restrict__ W2,
                                                ushort_t* __restrict__ whi,
                                                ushort_t* __restrict__ wlo) {
    int e = blockIdx.x * 256 + threadIdx.x;  // 4096 total
    int col = e & 63, k = e >> 6;
    float f = W2[(size_t)k * HID + col];
    ushort_t hi, lo;
    split_bf(f, hi, lo);
    int idx = col * 64 + (((k >> 3) ^ (col & 7)) << 3) + (k & 7);
    whi[idx] = hi;
    wlo[idx] = lo;
}

// ---------- zero the dummy row (index N) of each quarter of each u buffer ----------
__global__ void k_zero(ushort_t* __restrict__ u0, ushort_t* __restrict__ ua,
                       ushort_t* __restrict__ ub, int N) {
    const int t = threadIdx.x;
    if (t < 192) {
        ushort_t* bufs[3] = {u0, ua, ub};
        ushort_t* p = bufs[t >> 6];
        const int shard = (t & 63) >> 4, f = t & 15;
        p[((size_t)shard * (N + 1) + N) * 16 + f] = 0;
    }
}

// ---------- bin edges by dst>>9; packed record = src | (localnode<<20) ----------
__global__ __launch_bounds__(256) void k_bin(const int* __restrict__ ei,
                                             int* __restrict__ bcur,
                                             uint_t* __restrict__ binned, int E) {
    __shared__ int hist[NBKT];
    __shared__ int base[NBKT];
    const int t = threadIdx.x;
    const int c0 = blockIdx.x * 4096;
    hist[t] = 0;
    __syncthreads();
#pragma unroll
    for (int i = 0; i < 16; ++i) {
        int e = c0 + i * 256 + t;
        if (e < E) atomicAdd(&hist[ei[E + e] >> 9], 1);
    }
    __syncthreads();
    {
        int h = hist[t];
        base[t] = (h > 0) ? atomicAdd(&bcur[t], h) : 0;
        hist[t] = 0;  // reuse as local rank cursor
    }
    __syncthreads();
#pragma unroll
    for (int i = 0; i < 16; ++i) {
        int e = c0 + i * 256 + t;
        if (e < E) {
            int src = ei[e];
            int dst = ei[E + e];
            int b = dst >> 9;
            int r = atomicAdd(&hist[b], 1);
            int pos = base[b] + r;
            if (pos >= BCAP) pos = BCAP - 1;  // safety clamp
            binned[(size_t)b * BCAP + pos] = (uint_t)src | ((uint_t)(dst & 511) << 20);
        }
    }
}

// ---------- csrA: per-bucket counts, dinv, local padded offsets, bucket padded sum ----
__global__ __launch_bounds__(256) void k_csrA(const uint_t* __restrict__ binned,
                                              const int* __restrict__ bcur,
                                              int* __restrict__ cnt,
                                              float* __restrict__ dinv,
                                              int* __restrict__ offl,
                                              int* __restrict__ bpad, int N) {
    __shared__ int cl[512];
    __shared__ int ps[256];
    const int b = blockIdx.x, t = threadIdx.x;
    const int nE = bcur[b];
    const uint_t* be = binned + (size_t)b * BCAP;
    cl[t] = 0;
    cl[t + 256] = 0;
    __syncthreads();
    for (int i = t; i < nE; i += 256) atomicAdd(&cl[be[i] >> 20], 1);
    __syncthreads();
    const int ca = cl[2 * t], cb = cl[2 * t + 1];
    const int p4a = (ca + 3) & ~3, p4b = (cb + 3) & ~3;
    const int p = p4a + p4b;
    ps[t] = p;
    __syncthreads();
#pragma unroll
    for (int o = 1; o < 256; o <<= 1) {
        int add = (t >= o) ? ps[t - o] : 0;
        __syncthreads();
        ps[t] += add;
        __syncthreads();
    }
    const int pbase = ps[t] - p;
    const int g0 = b * 512 + 2 * t;
    if (g0 < N) {
        cnt[g0] = ca;
        dinv[g0] = rsqrtf((float)(ca + 1));
        offl[g0] = pbase;
    }
    if (g0 + 1 < N) {
        cnt[g0 + 1] = cb;
        dinv[g0 + 1] = rsqrtf((float)(cb + 1));
        offl[g0 + 1] = pbase + p4a;
    }
    if (t == 255) bpad[b] = ps[255];
}

// ---------- scan bucket padded totals -> bases; rowstart[N] = Epad ----------
__global__ __launch_bounds__(256) void k_bktscan(const int* __restrict__ bpad,
                                                 int* __restrict__ bbase,
                                                 int* __restrict__ rowstart, int N) {
    __shared__ int s[256];
    const int t = threadIdx.x;
    const int v = bpad[t];
    s[t] = v;
    __syncthreads();
#pragma unroll
    for (int off = 1; off < 256; off <<= 1) {
        int add = (t >= off) ? s[t - off] : 0;
        __syncthreads();
        s[t] += add;
        __syncthreads();
    }
    bbase[t] = s[t] - v;
    if (t == 255) rowstart[N] = s[255];
}

// ---------- csrB: rowstart, scatter srcs, fill padding with N ----------
__global__ __launch_bounds__(256) void k_csrB(const uint_t* __restrict__ binned,
                                              const int* __restrict__ bcur,
                                              const int* __restrict__ bbase,
                                              const int* __restrict__ offl,
                                              const int* __restrict__ cnt,
                                              int* __restrict__ csr,
                                              int* __restrict__ rowstart, int N) {
    __shared__ int st[512];
    __shared__ int cur[512];
    const int b = blockIdx.x, t = threadIdx.x;
    const int nE = bcur[b];
    const int gb = bbase[b];
    const uint_t* be = binned + (size_t)b * BCAP;
    const int n0 = b * 512;
    for (int i = t; i < 512; i += 256) {
        int g = n0 + i;
        int s = (g < N) ? gb + offl[g] : 0;
        st[i] = s;
        cur[i] = s;
        if (g < N) rowstart[g] = s;
    }
    __syncthreads();
    for (int i = t; i < nE; i += 256) {
        uint_t rec = be[i];
        int ln = rec >> 20;
        int r = atomicAdd(&cur[ln], 1);
        csr[r] = (int)(rec & 0xFFFFFu);
    }
    __syncthreads();
    for (int i = t; i < 512; i += 256) {
        int g = n0 + i;
        if (g < N) {
            int c = cnt[g];
            int end = st[i] + ((c + 3) & ~3);
            for (int j = st[i] + c; j < end; ++j) csr[j] = N;  // dummy -> zero row
        }
    }
}

// ---------- GEMM1 (MFMA) + gelu + LN: u0 = dinv * LN(gelu(x @ W1 + b1)) ----------
// 512 thr = 8 waves, wave -> 16 rows x 64 cols; W in 64KB LDS; all x preloaded.
// u0 written in packed quarter layout [q][(N+1)][16feat] bf16.
__global__ __launch_bounds__(512, 4) void k_gemm1ln(const float* __restrict__ x,
                                                    const ushort_t* __restrict__ whi,
                                                    const ushort_t* __restrict__ wlo,
                                                    const float* __restrict__ b1,
                                                    const float* __restrict__ g1,
                                                    const float* __restrict__ be1,
                                                    const float* __restrict__ dinv,
                                                    ushort_t* __restrict__ u0, int N) {
    __shared__ ushort_t Wh[16384];
    __shared__ ushort_t Wl[16384];
    const int t = threadIdx.x;
    {
        const uint4* s1 = (const uint4*)whi;
        uint4* d1 = (uint4*)Wh;
        for (int i = t; i < 2048; i += 512) d1[i] = s1[i];
        const uint4* s2 = (const uint4*)wlo;
        uint4* d2 = (uint4*)Wl;
        for (int i = t; i < 2048; i += 512) d2[i] = s2[i];
    }

    const int lane = t & 63, w = t >> 6;
    const int l15 = lane & 15, lg = lane >> 4;
    const int row0 = blockIdx.x * 128 + w * 16;
    int rowc = row0 + l15;
    if (rowc > N - 1) rowc = N - 1;
    const float* xr = x + (size_t)rowc * INC + lg * 8;

    float4 ax[16];
#pragma unroll
    for (int i = 0; i < 8; ++i) {
        ax[2 * i] = *(const float4*)(xr + i * 32);
        ax[2 * i + 1] = *(const float4*)(xr + i * 32 + 4);
    }
    __syncthreads();

    float4v acc[4];
#pragma unroll
    for (int i = 0; i < 4; ++i) acc[i] = (float4v){0.f, 0.f, 0.f, 0.f};

    union U8 { short8v v; ushort_t u[8]; };

#pragma unroll
    for (int t8 = 0; t8 < 8; ++t8) {
        U8 ahi, alo;
        {
            const float af[8] = {ax[2 * t8].x, ax[2 * t8].y, ax[2 * t8].z, ax[2 * t8].w,
                                 ax[2 * t8 + 1].x, ax[2 * t8 + 1].y, ax[2 * t8 + 1].z,
                                 ax[2 * t8 + 1].w};
#pragma unroll
            for (int j = 0; j < 8; ++j) split_bf(af[j], ahi.u[j], alo.u[j]);
        }
        const int kb = t8 * 4 + lg;
#pragma unroll
        for (int ct = 0; ct < 4; ++ct) {
            const int col = ct * 16 + l15;
            const int idx = col * 256 + ((kb ^ (col & 7)) << 3);
            const short8v bhi = *(const short8v*)&Wh[idx];
            const short8v blo = *(const short8v*)&Wl[idx];
            acc[ct] = __builtin_amdgcn_mfma_f32_16x16x32_bf16(ahi.v, bhi, acc[ct], 0, 0, 0);
            acc[ct] = __builtin_amdgcn_mfma_f32_16x16x32_bf16(ahi.v, blo, acc[ct], 0, 0, 0);
            acc[ct] = __builtin_amdgcn_mfma_f32_16x16x32_bf16(alo.v, bhi, acc[ct], 0, 0, 0);
        }
    }

    float b1c[4], g1c[4], bec[4];
#pragma unroll
    for (int ct = 0; ct < 4; ++ct) {
        const int col = ct * 16 + l15;
        b1c[ct] = b1[col];
        g1c[ct] = g1[col];
        bec[ct] = be1[col];
    }
    float gv[4][4];
#pragma unroll
    for (int ct = 0; ct < 4; ++ct)
#pragma unroll
        for (int r = 0; r < 4; ++r) gv[ct][r] = gelu_exact(acc[ct][r] + b1c[ct]);

    float mu[4], rsv[4];
#pragma unroll
    for (int r = 0; r < 4; ++r) {
        float p = gv[0][r] + gv[1][r] + gv[2][r] + gv[3][r];
        p += __shfl_xor(p, 1, 64);
        p += __shfl_xor(p, 2, 64);
        p += __shfl_xor(p, 4, 64);
        p += __shfl_xor(p, 8, 64);
        mu[r] = p * (1.0f / 64.0f);
        float d0 = gv[0][r] - mu[r], d1 = gv[1][r] - mu[r];
        float d2 = gv[2][r] - mu[r], d3 = gv[3][r] - mu[r];
        float p2 = d0 * d0 + d1 * d1 + d2 * d2 + d3 * d3;
        p2 += __shfl_xor(p2, 1, 64);
        p2 += __shfl_xor(p2, 2, 64);
        p2 += __shfl_xor(p2, 4, 64);
        p2 += __shfl_xor(p2, 8, 64);
        rsv[r] = rsqrtf(p2 * (1.0f / 64.0f) + LN_EPS);
    }
#pragma unroll
    for (int r = 0; r < 4; ++r) {
        const int row = row0 + lg * 4 + r;
        if (row < N) {
            const float di = dinv[row];
#pragma unroll
            for (int ct = 0; ct < 4; ++ct) {
                const float ln = (gv[ct][r] - mu[r]) * rsv[r] * g1c[ct] + bec[ct];
                u0[((size_t)ct * (N + 1) + row) * 16 + l15] = f2bf(di * ln);
            }
        }
    }
}

// ---------- APPNP step, TEMPORAL quarter phases in ONE dispatch ----------
// u' = (1-a)*dinv^2*(sum_adj u + u[self]) + a*u0, per 16-feature quarter.
// Grid is pass-major (pass = blockIdx>>14): the execution front sweeps the four
// quarters sequentially, so during each phase EVERY XCD's gather footprint is the
// same 3.2MB quarter (no XCD-affinity assumption). 2 nodes/wave; 4 edge slots x
// 8 lanes (uint = 2 bf16) per node; 8 edges in flight/node; pad-4 CSR, dummy -> row N.
__global__ __launch_bounds__(256) void k_prop(const ushort_t* __restrict__ uin,
                                              const ushort_t* __restrict__ u0,
                                              ushort_t* __restrict__ uout,
                                              const int* __restrict__ csr,
                                              const int* __restrict__ rowstart,
                                              const float* __restrict__ dinv,
                                              int N, int nbq) {
    const int pass = blockIdx.x >> 14;
    const int nb = blockIdx.x & 16383;
    if (nb >= nbq) return;
    const int t = threadIdx.x;
    const int lane = t & 63;
    const int node = nb * 8 + (t >> 6) * 2 + (lane >> 5);
    if (node >= N) return;
    const int s = (lane >> 3) & 3;  // edge slot 0..3
    const int fl = lane & 7;        // uint within 32B quarter-row
    const size_t qoff = (size_t)pass * (N + 1) * 8;
    const uint_t* Uq = (const uint_t*)uin + qoff;
    const int s0 = rowstart[node];
    const int e1 = rowstart[node + 1];
    float a0 = 0.f, a1 = 0.f;
    for (int e = s0; e < e1; e += 8) {
        const int i1 = csr[e + s];
        const uint_t v1 = Uq[(size_t)i1 * 8 + fl];
        a0 += bf_lo(v1);
        a1 += bf_hi(v1);
        if (e + 4 < e1) {
            const int i2 = csr[e + 4 + s];
            const uint_t v2 = Uq[(size_t)i2 * 8 + fl];
            a0 += bf_lo(v2);
            a1 += bf_hi(v2);
        }
    }
    a0 += __shfl_xor(a0, 8, 64);
    a0 += __shfl_xor(a0, 16, 64);
    a1 += __shfl_xor(a1, 8, 64);
    a1 += __shfl_xor(a1, 16, 64);
    if (s == 0) {
        const uint_t ud = Uq[(size_t)node * 8 + fl];
        const uint_t uz = ((const uint_t*)u0)[qoff + (size_t)node * 8 + fl];
        const float di = dinv[node];
        const float c = (1.0f - ALPHA) * di * di;
        const float r0 = c * (a0 + bf_lo(ud)) + ALPHA * bf_lo(uz);
        const float r1 = c * (a1 + bf_hi(ud)) + ALPHA * bf_hi(uz);
        ((uint_t*)uout)[qoff + (size_t)node * 8 + fl] =
            (uint_t)f2bf(r0) | ((uint_t)f2bf(r1) << 16);
    }
}

// ---------- final (MFMA): out = LN(gelu(u/dinv)) @ W2 + b2 (quarter-layout u) ----------
__global__ __launch_bounds__(256) void k_final(const ushort_t* __restrict__ u,
                                               const int* __restrict__ cnt,
                                               const float* __restrict__ g2,
                                               const float* __restrict__ be2,
                                               const ushort_t* __restrict__ w2hi,
                                               const ushort_t* __restrict__ w2lo,
                                               const float* __restrict__ b2,
                                               float* __restrict__ out, int N) {
    __shared__ ushort_t Wh[4096];
    __shared__ ushort_t Wl[4096];
    const int t = threadIdx.x;
    {
        const uint4* s1 = (const uint4*)w2hi;
        uint4* d1 = (uint4*)Wh;
        for (int i = t; i < 512; i += 256) d1[i] = s1[i];
        const uint4* s2 = (const uint4*)w2lo;
        uint4* d2 = (uint4*)Wl;
        for (int i = t; i < 512; i += 256) d2[i] = s2[i];
    }
    __syncthreads();

    const int lane = t & 63, w = t >> 6;
    const int l15 = lane & 15, lg = lane >> 4;
    const int row0 = blockIdx.x * 64 + w * 16;
    if (row0 >= N) return;
    int rowc = row0 + l15;
    if (rowc > N - 1) rowc = N - 1;

    // features lg*8..lg*8+7 -> quarter lg>>1, inner offset (lg&1)*8; +32 -> quarter +2
    const int oA = (lg & 1) * 8;
    const uint4 uva = *(const uint4*)(u + ((size_t)(lg >> 1) * (N + 1) + rowc) * 16 + oA);
    const uint4 uvb = *(const uint4*)(u + ((size_t)(2 + (lg >> 1)) * (N + 1) + rowc) * 16 + oA);
    const float sc = sqrtf((float)(cnt[rowc] + 1));  // 1/dinv

    float v[16];
    {
        const uint_t ua_[4] = {uva.x, uva.y, uva.z, uva.w};
        const uint_t ub_[4] = {uvb.x, uvb.y, uvb.z, uvb.w};
#pragma unroll
        for (int j = 0; j < 4; ++j) {
            v[2 * j] = gelu_exact(bf_lo(ua_[j]) * sc);
            v[2 * j + 1] = gelu_exact(bf_hi(ua_[j]) * sc);
            v[8 + 2 * j] = gelu_exact(bf_lo(ub_[j]) * sc);
            v[8 + 2 * j + 1] = gelu_exact(bf_hi(ub_[j]) * sc);
        }
    }
    float s = 0.f;
#pragma unroll
    for (int j = 0; j < 16; ++j) s += v[j];
    s += __shfl_xor(s, 16, 64);
    s += __shfl_xor(s, 32, 64);
    const float mu = s * (1.0f / 64.0f);
    float sq = 0.f;
#pragma unroll
    for (int j = 0; j < 16; ++j) {
        v[j] -= mu;
        sq += v[j] * v[j];
    }
    sq += __shfl_xor(sq, 16, 64);
    sq += __shfl_xor(sq, 32, 64);
    const float rs = rsqrtf(sq * (1.0f / 64.0f) + LN_EPS);

    union U8 { short8v v; ushort_t u[8]; };
    U8 a0, a1;
#pragma unroll
    for (int j = 0; j < 8; ++j) {
        const int ka = lg * 8 + j;
        const int kb = 32 + lg * 8 + j;
        a0.u[j] = f2bf(v[j] * rs * g2[ka] + be2[ka]);
        a1.u[j] = f2bf(v[8 + j] * rs * g2[kb] + be2[kb]);
    }

    float4v acc[4];
#pragma unroll
    for (int i = 0; i < 4; ++i) acc[i] = (float4v){0.f, 0.f, 0.f, 0.f};
#pragma unroll
    for (int ct = 0; ct < 4; ++ct) {
        const int col = ct * 16 + l15;
        const int i0 = col * 64 + ((lg ^ (col & 7)) << 3);
        const int i1 = col * 64 + (((4 + lg) ^ (col & 7)) << 3);
        short8v b0h = *(const short8v*)&Wh[i0];
        short8v b0l = *(const short8v*)&Wl[i0];
        short8v b1h = *(const short8v*)&Wh[i1];
        short8v b1l = *(const short8v*)&Wl[i1];
        acc[ct] = __builtin_amdgcn_mfma_f32_16x16x32_bf16(a0.v, b0h, acc[ct], 0, 0, 0);
        acc[ct] = __builtin_amdgcn_mfma_f32_16x16x32_bf16(a0.v, b0l, acc[ct], 0, 0, 0);
        acc[ct] = __builtin_amdgcn_mfma_f32_16x16x32_bf16(a1.v, b1h, acc[ct], 0, 0, 0);
        acc[ct] = __builtin_amdgcn_mfma_f32_16x16x32_bf16(a1.v, b1l, acc[ct], 0, 0, 0);
    }

#pragma unroll
    for (int ct = 0; ct < 4; ++ct) {
        const float bb = b2[ct * 16 + l15];
#pragma unroll
        for (int r = 0; r < 4; ++r) {
            const int row = row0 + lg * 4 + r;
            if (row < N) out[(size_t)row * HID + ct * 16 + l15] = acc[ct][r] + bb;
        }
    }
}

extern "C" void kernel_launch(void* const* d_in, const int* in_sizes, int n_in,
                              void* d_out, int out_size, void* d_ws, size_t ws_size,
                              hipStream_t stream) {
    const float* x   = (const float*)d_in[0];
    const int*   ei  = (const int*)d_in[1];
    const float* W1  = (const float*)d_in[2];
    const float* b1  = (const float*)d_in[3];
    const float* g1  = (const float*)d_in[4];
    const float* be1 = (const float*)d_in[5];
    const float* g2  = (const float*)d_in[6];
    const float* be2 = (const float*)d_in[7];
    const float* W2  = (const float*)d_in[8];
    const float* b2  = (const float*)d_in[9];
    float* out = (float*)d_out;

    const int N = in_sizes[0] / INC;
    const int E = in_sizes[1] / 2;

    char* ws = (char*)d_ws;
    size_t o = 0;
    auto alloc = [&](size_t bytes) { size_t r = o; o += (bytes + 255) & ~(size_t)255; return r; };
    ushort_t* u0 = (ushort_t*)(ws + alloc((size_t)(N + 1) * HID * 2));
    ushort_t* ua = (ushort_t*)(ws + alloc((size_t)(N + 1) * HID * 2));
    ushort_t* ub = (ushort_t*)(ws + alloc((size_t)(N + 1) * HID * 2));
    float* dinv     = (float*)(ws + alloc((size_t)N * 4));
    int*   cnt      = (int*)(ws + alloc((size_t)N * 4));
    int*   offl     = (int*)(ws + alloc((size_t)N * 4));
    int*   rowstart = (int*)(ws + alloc((size_t)(N + 1) * 4));
    int*   bcur     = (int*)(ws + alloc(NBKT * 4));
    int*   bpad     = (int*)(ws + alloc(NBKT * 4));
    int*   bbase    = (int*)(ws + alloc(NBKT * 4));
    ushort_t* whi   = (ushort_t*)(ws + alloc(16384 * 2));
    ushort_t* wlo   = (ushort_t*)(ws + alloc(16384 * 2));
    ushort_t* w2hi  = (ushort_t*)(ws + alloc(4096 * 2));
    ushort_t* w2lo  = (ushort_t*)(ws + alloc(4096 * 2));
    uint_t* binned  = (uint_t*)(ws + alloc((size_t)NBKT * BCAP * 4));
    int*   csr      = (int*)(ws + alloc((size_t)(E + 3 * (size_t)N + 256) * 4));

    const int nbkt = (N + 511) / 512;  // 196 for N=100000
    const int nbq = (N + 7) / 8;       // node-blocks (8 nodes/block) per quarter-phase

    hipMemsetAsync(bcur, 0, NBKT * 4, stream);
    hipMemsetAsync(bpad, 0, NBKT * 4, stream);

    k_zero<<<1, 256, 0, stream>>>(u0, ua, ub, N);
    k_prepW<<<64, 256, 0, stream>>>(W1, whi, wlo);
    k_prepW2<<<16, 256, 0, stream>>>(W2, w2hi, w2lo);
    k_bin<<<(E + 4095) / 4096, 256, 0, stream>>>(ei, bcur, binned, E);
    k_csrA<<<nbkt, 256, 0, stream>>>(binned, bcur, cnt, dinv, offl, bpad, N);
    k_bktscan<<<1, 256, 0, stream>>>(bpad, bbase, rowstart, N);
    k_csrB<<<nbkt, 256, 0, stream>>>(binned, bcur, bbase, offl, cnt, csr, rowstart, N);
    k_gemm1ln<<<(N + 127) / 128, 512, 0, stream>>>(x, whi, wlo, b1, g1, be1, dinv, u0, N);

    ushort_t* bufs[2] = {ua, ub};
    const ushort_t* pin = u0;
    for (int k = 0; k < 10; ++k) {
        ushort_t* pout = bufs[k & 1];
        k_prop<<<4 * 16384, 256, 0, stream>>>(pin, u0, pout, csr, rowstart, dinv, N, nbq);
        pin = pout;
    }
    k_final<<<(N + 63) / 64, 256, 0, stream>>>(pin, cnt, g2, be2, w2hi, w2lo, b2, out, N);
}

// Round 10
// 525.917 us; speedup vs baseline: 2.2252x; 2.2252x over previous
//
#include <hip/hip_runtime.h>
#include <math.h>

#define HID 64
#define INC 256
#define LN_EPS 1e-5f
#define ALPHA 0.1f
#define NBKT 256     // max buckets (N<=131072); actual = ceil(N/512)
#define BCAP 12288   // per-bucket capacity; E/N*512 = 8192 expected, +45 sigma margin

typedef unsigned short ushort_t;
typedef unsigned int uint_t;
using short8v = __attribute__((ext_vector_type(8))) short;
using float4v = __attribute__((ext_vector_type(4))) float;

__device__ __forceinline__ float gelu_exact(float x) {
    return 0.5f * x * (1.0f + erff(x * 0.70710678118654752f));
}

__device__ __forceinline__ ushort_t f2bf(float f) {
    uint_t u = __float_as_uint(f);
    return (ushort_t)((u + 0x7fffu + ((u >> 16) & 1u)) >> 16);
}
__device__ __forceinline__ float bf_lo(uint_t v) { return __uint_as_float(v << 16); }
__device__ __forceinline__ float bf_hi(uint_t v) { return __uint_as_float(v & 0xffff0000u); }

__device__ __forceinline__ void split_bf(float f, ushort_t& hi, ushort_t& lo) {
    uint_t ub = __float_as_uint(f);
    uint_t h = (ub + 0x7fffu + ((ub >> 16) & 1u)) >> 16;
    hi = (ushort_t)h;
    float fl = f - __uint_as_float(h << 16);
    uint_t lb = __float_as_uint(fl);
    lo = (ushort_t)((lb + 0x7fffu + ((lb >> 16) & 1u)) >> 16);
}

// ---------- prep: W1 [256][64] f32 -> swizzled W^T bf16 hi/lo [64][256] ----------
__global__ __launch_bounds__(256) void k_prepW(const float* __restrict__ W1,
                                               ushort_t* __restrict__ whi,
                                               ushort_t* __restrict__ wlo) {
    int e = blockIdx.x * 256 + threadIdx.x;  // 16384 total
    int col = e & 63, k = e >> 6;
    float f = W1[(size_t)k * HID + col];
    ushort_t hi, lo;
    split_bf(f, hi, lo);
    int idx = col * 256 + (((k >> 3) ^ (col & 7)) << 3) + (k & 7);
    whi[idx] = hi;
    wlo[idx] = lo;
}

// ---------- prep: W2 [64][64] f32 -> swizzled W^T bf16 hi/lo [64][64] ----------
__global__ __launch_bounds__(256) void k_prepW2(const float* __restrict__ W2,
                                                ushort_t* __restrict__ whi,
                                                ushort_t* __restrict__ wlo) {
    int e = blockIdx.x * 256 + threadIdx.x;  // 4096 total
    int col = e & 63, k = e >> 6;
    float f = W2[(size_t)k * HID + col];
    ushort_t hi, lo;
    split_bf(f, hi, lo);
    int idx = col * 64 + (((k >> 3) ^ (col & 7)) << 3) + (k & 7);
    whi[idx] = hi;
    wlo[idx] = lo;
}

// ---------- bin edges by dst>>9; packed record = src | (localnode<<20) ----------
__global__ __launch_bounds__(256) void k_bin(const int* __restrict__ ei,
                                             int* __restrict__ bcur,
                                             uint_t* __restrict__ binned, int E) {
    __shared__ int hist[NBKT];
    __shared__ int base[NBKT];
    const int t = threadIdx.x;
    const int c0 = blockIdx.x * 4096;
    hist[t] = 0;
    __syncthreads();
#pragma unroll
    for (int i = 0; i < 16; ++i) {
        int e = c0 + i * 256 + t;
        if (e < E) atomicAdd(&hist[ei[E + e] >> 9], 1);
    }
    __syncthreads();
    {
        int h = hist[t];
        base[t] = (h > 0) ? atomicAdd(&bcur[t], h) : 0;
        hist[t] = 0;  // reuse as local rank cursor
    }
    __syncthreads();
#pragma unroll
    for (int i = 0; i < 16; ++i) {
        int e = c0 + i * 256 + t;
        if (e < E) {
            int src = ei[e];
            int dst = ei[E + e];
            int b = dst >> 9;
            int r = atomicAdd(&hist[b], 1);
            int pos = base[b] + r;
            if (pos >= BCAP) pos = BCAP - 1;  // safety clamp
            binned[(size_t)b * BCAP + pos] = (uint_t)src | ((uint_t)(dst & 511) << 20);
        }
    }
}

// ---------- csrA: per-bucket counts, dinv, local padded offsets, bucket padded sum ----
__global__ __launch_bounds__(256) void k_csrA(const uint_t* __restrict__ binned,
                                              const int* __restrict__ bcur,
                                              int* __restrict__ cnt,
                                              float* __restrict__ dinv,
                                              int* __restrict__ offl,
                                              int* __restrict__ bpad, int N) {
    __shared__ int cl[512];
    __shared__ int ps[256];
    const int b = blockIdx.x, t = threadIdx.x;
    const int nE = bcur[b];
    const uint_t* be = binned + (size_t)b * BCAP;
    cl[t] = 0;
    cl[t + 256] = 0;
    __syncthreads();
    for (int i = t; i < nE; i += 256) atomicAdd(&cl[be[i] >> 20], 1);
    __syncthreads();
    const int ca = cl[2 * t], cb = cl[2 * t + 1];
    const int p4a = (ca + 3) & ~3, p4b = (cb + 3) & ~3;
    const int p = p4a + p4b;
    ps[t] = p;
    __syncthreads();
#pragma unroll
    for (int o = 1; o < 256; o <<= 1) {
        int add = (t >= o) ? ps[t - o] : 0;
        __syncthreads();
        ps[t] += add;
        __syncthreads();
    }
    const int pbase = ps[t] - p;
    const int g0 = b * 512 + 2 * t;
    if (g0 < N) {
        cnt[g0] = ca;
        dinv[g0] = rsqrtf((float)(ca + 1));
        offl[g0] = pbase;
    }
    if (g0 + 1 < N) {
        cnt[g0 + 1] = cb;
        dinv[g0 + 1] = rsqrtf((float)(cb + 1));
        offl[g0 + 1] = pbase + p4a;
    }
    if (t == 255) bpad[b] = ps[255];
}

// ---------- scan bucket padded totals -> bases; rowstart[N] = Epad ----------
__global__ __launch_bounds__(256) void k_bktscan(const int* __restrict__ bpad,
                                                 int* __restrict__ bbase,
                                                 int* __restrict__ rowstart, int N) {
    __shared__ int s[256];
    const int t = threadIdx.x;
    const int v = bpad[t];
    s[t] = v;
    __syncthreads();
#pragma unroll
    for (int off = 1; off < 256; off <<= 1) {
        int add = (t >= off) ? s[t - off] : 0;
        __syncthreads();
        s[t] += add;
        __syncthreads();
    }
    bbase[t] = s[t] - v;
    if (t == 255) rowstart[N] = s[255];
}

// ---------- csrB: rowstart, scatter srcs, fill padding with N ----------
__global__ __launch_bounds__(256) void k_csrB(const uint_t* __restrict__ binned,
                                              const int* __restrict__ bcur,
                                              const int* __restrict__ bbase,
                                              const int* __restrict__ offl,
                                              const int* __restrict__ cnt,
                                              int* __restrict__ csr,
                                              int* __restrict__ rowstart, int N) {
    __shared__ int st[512];
    __shared__ int cur[512];
    const int b = blockIdx.x, t = threadIdx.x;
    const int nE = bcur[b];
    const int gb = bbase[b];
    const uint_t* be = binned + (size_t)b * BCAP;
    const int n0 = b * 512;
    for (int i = t; i < 512; i += 256) {
        int g = n0 + i;
        int s = (g < N) ? gb + offl[g] : 0;
        st[i] = s;
        cur[i] = s;
        if (g < N) rowstart[g] = s;
    }
    __syncthreads();
    for (int i = t; i < nE; i += 256) {
        uint_t rec = be[i];
        int ln = rec >> 20;
        int r = atomicAdd(&cur[ln], 1);
        csr[r] = (int)(rec & 0xFFFFFu);
    }
    __syncthreads();
    for (int i = t; i < 512; i += 256) {
        int g = n0 + i;
        if (g < N) {
            int c = cnt[g];
            int end = st[i] + ((c + 3) & ~3);
            for (int j = st[i] + c; j < end; ++j) csr[j] = N;  // dummy -> zero row
        }
    }
}

// ---------- GEMM1 (MFMA) + gelu + LN: u0 = dinv * LN(gelu(x @ W1 + b1)) ----------
// 512 thr = 8 waves, wave -> 16 rows x 64 cols; W in 64KB LDS; all x preloaded.
// u0 row-major [N+1][64] bf16.
__global__ __launch_bounds__(512, 4) void k_gemm1ln(const float* __restrict__ x,
                                                    const ushort_t* __restrict__ whi,
                                                    const ushort_t* __restrict__ wlo,
                                                    const float* __restrict__ b1,
                                                    const float* __restrict__ g1,
                                                    const float* __restrict__ be1,
                                                    const float* __restrict__ dinv,
                                                    ushort_t* __restrict__ u0, int N) {
    __shared__ ushort_t Wh[16384];
    __shared__ ushort_t Wl[16384];
    const int t = threadIdx.x;
    {
        const uint4* s1 = (const uint4*)whi;
        uint4* d1 = (uint4*)Wh;
        for (int i = t; i < 2048; i += 512) d1[i] = s1[i];
        const uint4* s2 = (const uint4*)wlo;
        uint4* d2 = (uint4*)Wl;
        for (int i = t; i < 2048; i += 512) d2[i] = s2[i];
    }

    const int lane = t & 63, w = t >> 6;
    const int l15 = lane & 15, lg = lane >> 4;
    const int row0 = blockIdx.x * 128 + w * 16;
    int rowc = row0 + l15;
    if (rowc > N - 1) rowc = N - 1;
    const float* xr = x + (size_t)rowc * INC + lg * 8;

    float4 ax[16];
#pragma unroll
    for (int i = 0; i < 8; ++i) {
        ax[2 * i] = *(const float4*)(xr + i * 32);
        ax[2 * i + 1] = *(const float4*)(xr + i * 32 + 4);
    }
    __syncthreads();

    float4v acc[4];
#pragma unroll
    for (int i = 0; i < 4; ++i) acc[i] = (float4v){0.f, 0.f, 0.f, 0.f};

    union U8 { short8v v; ushort_t u[8]; };

#pragma unroll
    for (int t8 = 0; t8 < 8; ++t8) {
        U8 ahi, alo;
        {
            const float af[8] = {ax[2 * t8].x, ax[2 * t8].y, ax[2 * t8].z, ax[2 * t8].w,
                                 ax[2 * t8 + 1].x, ax[2 * t8 + 1].y, ax[2 * t8 + 1].z,
                                 ax[2 * t8 + 1].w};
#pragma unroll
            for (int j = 0; j < 8; ++j) split_bf(af[j], ahi.u[j], alo.u[j]);
        }
        const int kb = t8 * 4 + lg;
#pragma unroll
        for (int ct = 0; ct < 4; ++ct) {
            const int col = ct * 16 + l15;
            const int idx = col * 256 + ((kb ^ (col & 7)) << 3);
            const short8v bhi = *(const short8v*)&Wh[idx];
            const short8v blo = *(const short8v*)&Wl[idx];
            acc[ct] = __builtin_amdgcn_mfma_f32_16x16x32_bf16(ahi.v, bhi, acc[ct], 0, 0, 0);
            acc[ct] = __builtin_amdgcn_mfma_f32_16x16x32_bf16(ahi.v, blo, acc[ct], 0, 0, 0);
            acc[ct] = __builtin_amdgcn_mfma_f32_16x16x32_bf16(alo.v, bhi, acc[ct], 0, 0, 0);
        }
    }

    float b1c[4], g1c[4], bec[4];
#pragma unroll
    for (int ct = 0; ct < 4; ++ct) {
        const int col = ct * 16 + l15;
        b1c[ct] = b1[col];
        g1c[ct] = g1[col];
        bec[ct] = be1[col];
    }
    float gv[4][4];
#pragma unroll
    for (int ct = 0; ct < 4; ++ct)
#pragma unroll
        for (int r = 0; r < 4; ++r) gv[ct][r] = gelu_exact(acc[ct][r] + b1c[ct]);

    float mu[4], rsv[4];
#pragma unroll
    for (int r = 0; r < 4; ++r) {
        float p = gv[0][r] + gv[1][r] + gv[2][r] + gv[3][r];
        p += __shfl_xor(p, 1, 64);
        p += __shfl_xor(p, 2, 64);
        p += __shfl_xor(p, 4, 64);
        p += __shfl_xor(p, 8, 64);
        mu[r] = p * (1.0f / 64.0f);
        float d0 = gv[0][r] - mu[r], d1 = gv[1][r] - mu[r];
        float d2 = gv[2][r] - mu[r], d3 = gv[3][r] - mu[r];
        float p2 = d0 * d0 + d1 * d1 + d2 * d2 + d3 * d3;
        p2 += __shfl_xor(p2, 1, 64);
        p2 += __shfl_xor(p2, 2, 64);
        p2 += __shfl_xor(p2, 4, 64);
        p2 += __shfl_xor(p2, 8, 64);
        rsv[r] = rsqrtf(p2 * (1.0f / 64.0f) + LN_EPS);
    }
#pragma unroll
    for (int r = 0; r < 4; ++r) {
        const int row = row0 + lg * 4 + r;
        if (row < N) {
            const float di = dinv[row];
#pragma unroll
            for (int ct = 0; ct < 4; ++ct) {
                const float ln = (gv[ct][r] - mu[r]) * rsv[r] * g1c[ct] + bec[ct];
                u0[(size_t)row * HID + ct * 16 + l15] = f2bf(di * ln);
            }
        }
    }
}

// ---------- APPNP step in u-space, deep-MLP ----------
// u' = (1-a)*dinv^2*(sum_adj u + u[self]) + a*u0. Wave per node; 16 lanes per edge
// (uint2 = 4 bf16). Both index int4s (32 edges) loaded up front, masked against the
// padded row length, then ALL 8 gathers issued in one round. Rare deg>32 tail loops.
__global__ __launch_bounds__(256) void k_prop(const ushort_t* __restrict__ uin,
                                              const ushort_t* __restrict__ u0,
                                              ushort_t* __restrict__ uout,
                                              const int* __restrict__ csr,
                                              const int* __restrict__ rowstart,
                                              const float* __restrict__ dinv, int N) {
    const int t = threadIdx.x;
    const int lane = t & 63;
    const int q = lane >> 4, fl = lane & 15;
    const int node = blockIdx.x * 4 + (t >> 6);
    if (node >= N) return;
    const uint2* U = (const uint2*)uin;
    const int s0 = rowstart[node];
    const int e1 = rowstart[node + 1];
    const int r = e1 - s0;  // multiple of 4

    // independent loads issued early
    const uint2 ud = U[(size_t)node * 16 + fl];
    const uint2 uz = ((const uint2*)u0)[(size_t)node * 16 + fl];
    const float di = dinv[node];

    const int oa = 4 * q;       // 0,4,8,12
    const int ob = 16 + 4 * q;  // 16,20,24,28
    int4 ia = make_int4(N, N, N, N);
    int4 ib = make_int4(N, N, N, N);
    if (oa < r) ia = *(const int4*)(csr + s0 + oa);
    if (ob < r) ib = *(const int4*)(csr + s0 + ob);

    const uint2 va0 = U[(size_t)ia.x * 16 + fl];
    const uint2 va1 = U[(size_t)ia.y * 16 + fl];
    const uint2 va2 = U[(size_t)ia.z * 16 + fl];
    const uint2 va3 = U[(size_t)ia.w * 16 + fl];
    const uint2 vb0 = U[(size_t)ib.x * 16 + fl];
    const uint2 vb1 = U[(size_t)ib.y * 16 + fl];
    const uint2 vb2 = U[(size_t)ib.z * 16 + fl];
    const uint2 vb3 = U[(size_t)ib.w * 16 + fl];

    float a0 = bf_lo(va0.x) + bf_lo(va1.x) + bf_lo(va2.x) + bf_lo(va3.x)
             + bf_lo(vb0.x) + bf_lo(vb1.x) + bf_lo(vb2.x) + bf_lo(vb3.x);
    float a1 = bf_hi(va0.x) + bf_hi(va1.x) + bf_hi(va2.x) + bf_hi(va3.x)
             + bf_hi(vb0.x) + bf_hi(vb1.x) + bf_hi(vb2.x) + bf_hi(vb3.x);
    float a2 = bf_lo(va0.y) + bf_lo(va1.y) + bf_lo(va2.y) + bf_lo(va3.y)
             + bf_lo(vb0.y) + bf_lo(vb1.y) + bf_lo(vb2.y) + bf_lo(vb3.y);
    float a3 = bf_hi(va0.y) + bf_hi(va1.y) + bf_hi(va2.y) + bf_hi(va3.y)
             + bf_hi(vb0.y) + bf_hi(vb1.y) + bf_hi(vb2.y) + bf_hi(vb3.y);

    // rare tail: degree > 32
    for (int e = s0 + 32; e < e1; e += 16) {
        const int ge = e + 4 * q;
        int4 id = make_int4(N, N, N, N);
        if (ge < e1) id = *(const int4*)(csr + ge);
        const uint2 v0 = U[(size_t)id.x * 16 + fl];
        const uint2 v1 = U[(size_t)id.y * 16 + fl];
        const uint2 v2 = U[(size_t)id.z * 16 + fl];
        const uint2 v3 = U[(size_t)id.w * 16 + fl];
        a0 += bf_lo(v0.x) + bf_lo(v1.x) + bf_lo(v2.x) + bf_lo(v3.x);
        a1 += bf_hi(v0.x) + bf_hi(v1.x) + bf_hi(v2.x) + bf_hi(v3.x);
        a2 += bf_lo(v0.y) + bf_lo(v1.y) + bf_lo(v2.y) + bf_lo(v3.y);
        a3 += bf_hi(v0.y) + bf_hi(v1.y) + bf_hi(v2.y) + bf_hi(v3.y);
    }

    a0 += __shfl_xor(a0, 16, 64); a0 += __shfl_xor(a0, 32, 64);
    a1 += __shfl_xor(a1, 16, 64); a1 += __shfl_xor(a1, 32, 64);
    a2 += __shfl_xor(a2, 16, 64); a2 += __shfl_xor(a2, 32, 64);
    a3 += __shfl_xor(a3, 16, 64); a3 += __shfl_xor(a3, 32, 64);
    if (lane < 16) {
        const float c = (1.0f - ALPHA) * di * di;
        const float r0 = c * (a0 + bf_lo(ud.x)) + ALPHA * bf_lo(uz.x);
        const float r1 = c * (a1 + bf_hi(ud.x)) + ALPHA * bf_hi(uz.x);
        const float r2 = c * (a2 + bf_lo(ud.y)) + ALPHA * bf_lo(uz.y);
        const float r3 = c * (a3 + bf_hi(ud.y)) + ALPHA * bf_hi(uz.y);
        uint2 o;
        o.x = (uint_t)f2bf(r0) | ((uint_t)f2bf(r1) << 16);
        o.y = (uint_t)f2bf(r2) | ((uint_t)f2bf(r3) << 16);
        ((uint2*)uout)[(size_t)node * 16 + fl] = o;
    }
}

// ---------- final (MFMA): out = LN(gelu(u/dinv)) @ W2 + b2 ----------
__global__ __launch_bounds__(256) void k_final(const ushort_t* __restrict__ u,
                                               const int* __restrict__ cnt,
                                               const float* __restrict__ g2,
                                               const float* __restrict__ be2,
                                               const ushort_t* __restrict__ w2hi,
                                               const ushort_t* __restrict__ w2lo,
                                               const float* __restrict__ b2,
                                               float* __restrict__ out, int N) {
    __shared__ ushort_t Wh[4096];
    __shared__ ushort_t Wl[4096];
    const int t = threadIdx.x;
    {
        const uint4* s1 = (const uint4*)w2hi;
        uint4* d1 = (uint4*)Wh;
        for (int i = t; i < 512; i += 256) d1[i] = s1[i];
        const uint4* s2 = (const uint4*)w2lo;
        uint4* d2 = (uint4*)Wl;
        for (int i = t; i < 512; i += 256) d2[i] = s2[i];
    }
    __syncthreads();

    const int lane = t & 63, w = t >> 6;
    const int l15 = lane & 15, lg = lane >> 4;
    const int row0 = blockIdx.x * 64 + w * 16;
    if (row0 >= N) return;
    int rowc = row0 + l15;
    if (rowc > N - 1) rowc = N - 1;

    const uint4 uva = *(const uint4*)(u + (size_t)rowc * HID + lg * 8);
    const uint4 uvb = *(const uint4*)(u + (size_t)rowc * HID + 32 + lg * 8);
    const float sc = sqrtf((float)(cnt[rowc] + 1));  // 1/dinv

    float v[16];
    {
        const uint_t ua_[4] = {uva.x, uva.y, uva.z, uva.w};
        const uint_t ub_[4] = {uvb.x, uvb.y, uvb.z, uvb.w};
#pragma unroll
        for (int j = 0; j < 4; ++j) {
            v[2 * j] = gelu_exact(bf_lo(ua_[j]) * sc);
            v[2 * j + 1] = gelu_exact(bf_hi(ua_[j]) * sc);
            v[8 + 2 * j] = gelu_exact(bf_lo(ub_[j]) * sc);
            v[8 + 2 * j + 1] = gelu_exact(bf_hi(ub_[j]) * sc);
        }
    }
    float s = 0.f;
#pragma unroll
    for (int j = 0; j < 16; ++j) s += v[j];
    s += __shfl_xor(s, 16, 64);
    s += __shfl_xor(s, 32, 64);
    const float mu = s * (1.0f / 64.0f);
    float sq = 0.f;
#pragma unroll
    for (int j = 0; j < 16; ++j) {
        v[j] -= mu;
        sq += v[j] * v[j];
    }
    sq += __shfl_xor(sq, 16, 64);
    sq += __shfl_xor(sq, 32, 64);
    const float rs = rsqrtf(sq * (1.0f / 64.0f) + LN_EPS);

    union U8 { short8v v; ushort_t u[8]; };
    U8 a0, a1;
#pragma unroll
    for (int j = 0; j < 8; ++j) {
        const int ka = lg * 8 + j;
        const int kb = 32 + lg * 8 + j;
        a0.u[j] = f2bf(v[j] * rs * g2[ka] + be2[ka]);
        a1.u[j] = f2bf(v[8 + j] * rs * g2[kb] + be2[kb]);
    }

    float4v acc[4];
#pragma unroll
    for (int i = 0; i < 4; ++i) acc[i] = (float4v){0.f, 0.f, 0.f, 0.f};
#pragma unroll
    for (int ct = 0; ct < 4; ++ct) {
        const int col = ct * 16 + l15;
        const int i0 = col * 64 + ((lg ^ (col & 7)) << 3);
        const int i1 = col * 64 + (((4 + lg) ^ (col & 7)) << 3);
        short8v b0h = *(const short8v*)&Wh[i0];
        short8v b0l = *(const short8v*)&Wl[i0];
        short8v b1h = *(const short8v*)&Wh[i1];
        short8v b1l = *(const short8v*)&Wl[i1];
        acc[ct] = __builtin_amdgcn_mfma_f32_16x16x32_bf16(a0.v, b0h, acc[ct], 0, 0, 0);
        acc[ct] = __builtin_amdgcn_mfma_f32_16x16x32_bf16(a0.v, b0l, acc[ct], 0, 0, 0);
        acc[ct] = __builtin_amdgcn_mfma_f32_16x16x32_bf16(a1.v, b1h, acc[ct], 0, 0, 0);
        acc[ct] = __builtin_amdgcn_mfma_f32_16x16x32_bf16(a1.v, b1l, acc[ct], 0, 0, 0);
    }

#pragma unroll
    for (int ct = 0; ct < 4; ++ct) {
        const float bb = b2[ct * 16 + l15];
#pragma unroll
        for (int r = 0; r < 4; ++r) {
            const int row = row0 + lg * 4 + r;
            if (row < N) out[(size_t)row * HID + ct * 16 + l15] = acc[ct][r] + bb;
        }
    }
}

extern "C" void kernel_launch(void* const* d_in, const int* in_sizes, int n_in,
                              void* d_out, int out_size, void* d_ws, size_t ws_size,
                              hipStream_t stream) {
    const float* x   = (const float*)d_in[0];
    const int*   ei  = (const int*)d_in[1];
    const float* W1  = (const float*)d_in[2];
    const float* b1  = (const float*)d_in[3];
    const float* g1  = (const float*)d_in[4];
    const float* be1 = (const float*)d_in[5];
    const float* g2  = (const float*)d_in[6];
    const float* be2 = (const float*)d_in[7];
    const float* W2  = (const float*)d_in[8];
    const float* b2  = (const float*)d_in[9];
    float* out = (float*)d_out;

    const int N = in_sizes[0] / INC;
    const int E = in_sizes[1] / 2;

    char* ws = (char*)d_ws;
    size_t o = 0;
    auto alloc = [&](size_t bytes) { size_t r = o; o += (bytes + 255) & ~(size_t)255; return r; };
    ushort_t* u0 = (ushort_t*)(ws + alloc((size_t)(N + 1) * HID * 2));
    ushort_t* ua = (ushort_t*)(ws + alloc((size_t)(N + 1) * HID * 2));
    ushort_t* ub = (ushort_t*)(ws + alloc((size_t)(N + 1) * HID * 2));
    float* dinv     = (float*)(ws + alloc((size_t)N * 4));
    int*   cnt      = (int*)(ws + alloc((size_t)N * 4));
    int*   offl     = (int*)(ws + alloc((size_t)N * 4));
    int*   rowstart = (int*)(ws + alloc((size_t)(N + 1) * 4));
    int*   bcur     = (int*)(ws + alloc(NBKT * 4));
    int*   bpad     = (int*)(ws + alloc(NBKT * 4));
    int*   bbase    = (int*)(ws + alloc(NBKT * 4));
    ushort_t* whi   = (ushort_t*)(ws + alloc(16384 * 2));
    ushort_t* wlo   = (ushort_t*)(ws + alloc(16384 * 2));
    ushort_t* w2hi  = (ushort_t*)(ws + alloc(4096 * 2));
    ushort_t* w2lo  = (ushort_t*)(ws + alloc(4096 * 2));
    uint_t* binned  = (uint_t*)(ws + alloc((size_t)NBKT * BCAP * 4));
    int*   csr      = (int*)(ws + alloc((size_t)(E + 3 * (size_t)N + 256) * 4));

    const int nbkt = (N + 511) / 512;  // 196 for N=100000

    hipMemsetAsync(bcur, 0, NBKT * 4, stream);
    hipMemsetAsync(bpad, 0, NBKT * 4, stream);
    // zero dummy row N of each u buffer (gather target for CSR padding)
    hipMemsetAsync(u0 + (size_t)N * HID, 0, HID * 2, stream);
    hipMemsetAsync(ua + (size_t)N * HID, 0, HID * 2, stream);
    hipMemsetAsync(ub + (size_t)N * HID, 0, HID * 2, stream);

    k_prepW<<<64, 256, 0, stream>>>(W1, whi, wlo);
    k_prepW2<<<16, 256, 0, stream>>>(W2, w2hi, w2lo);
    k_bin<<<(E + 4095) / 4096, 256, 0, stream>>>(ei, bcur, binned, E);
    k_csrA<<<nbkt, 256, 0, stream>>>(binned, bcur, cnt, dinv, offl, bpad, N);
    k_bktscan<<<1, 256, 0, stream>>>(bpad, bbase, rowstart, N);
    k_csrB<<<nbkt, 256, 0, stream>>>(binned, bcur, bbase, offl, cnt, csr, rowstart, N);
    k_gemm1ln<<<(N + 127) / 128, 512, 0, stream>>>(x, whi, wlo, b1, g1, be1, dinv, u0, N);

    ushort_t* bufs[2] = {ua, ub};
    const ushort_t* pin = u0;
    for (int k = 0; k < 10; ++k) {
        ushort_t* pout = bufs[k & 1];
        k_prop<<<(N + 3) / 4, 256, 0, stream>>>(pin, u0, pout, csr, rowstart, dinv, N);
        pin = pout;
    }
    k_final<<<(N + 63) / 64, 256, 0, stream>>>(pin, cnt, g2, be2, w2hi, w2lo, b2, out, N);
}

// Round 11
// 517.686 us; speedup vs baseline: 2.2606x; 1.0159x over previous
//
#include <hip/hip_runtime.h>
#include <math.h>

#define HID 64
#define INC 256
#define LN_EPS 1e-5f
#define ALPHA 0.1f
#define NBKT 256     // max buckets (N<=131072); actual = ceil(N/512)
#define BCAP 12288   // per-bucket capacity; E/N*512 = 8192 expected, +45 sigma margin

typedef unsigned short ushort_t;
typedef unsigned int uint_t;
using short8v = __attribute__((ext_vector_type(8))) short;
using float4v = __attribute__((ext_vector_type(4))) float;

__device__ __forceinline__ float gelu_exact(float x) {
    return 0.5f * x * (1.0f + erff(x * 0.70710678118654752f));
}

__device__ __forceinline__ ushort_t f2bf(float f) {
    uint_t u = __float_as_uint(f);
    return (ushort_t)((u + 0x7fffu + ((u >> 16) & 1u)) >> 16);
}
__device__ __forceinline__ float bf_lo(uint_t v) { return __uint_as_float(v << 16); }
__device__ __forceinline__ float bf_hi(uint_t v) { return __uint_as_float(v & 0xffff0000u); }

__device__ __forceinline__ void split_bf(float f, ushort_t& hi, ushort_t& lo) {
    uint_t ub = __float_as_uint(f);
    uint_t h = (ub + 0x7fffu + ((ub >> 16) & 1u)) >> 16;
    hi = (ushort_t)h;
    float fl = f - __uint_as_float(h << 16);
    uint_t lb = __float_as_uint(fl);
    lo = (ushort_t)((lb + 0x7fffu + ((lb >> 16) & 1u)) >> 16);
}

// ---------- prep: W1 [256][64] f32 -> swizzled W^T bf16 hi/lo [64][256] ----------
__global__ __launch_bounds__(256) void k_prepW(const float* __restrict__ W1,
                                               ushort_t* __restrict__ whi,
                                               ushort_t* __restrict__ wlo) {
    int e = blockIdx.x * 256 + threadIdx.x;  // 16384 total
    int col = e & 63, k = e >> 6;
    float f = W1[(size_t)k * HID + col];
    ushort_t hi, lo;
    split_bf(f, hi, lo);
    int idx = col * 256 + (((k >> 3) ^ (col & 7)) << 3) + (k & 7);
    whi[idx] = hi;
    wlo[idx] = lo;
}

// ---------- prep: W2 [64][64] f32 -> swizzled W^T bf16 hi/lo [64][64] ----------
__global__ __launch_bounds__(256) void k_prepW2(const float* __restrict__ W2,
                                                ushort_t* __restrict__ whi,
                                                ushort_t* __restrict__ wlo) {
    int e = blockIdx.x * 256 + threadIdx.x;  // 4096 total
    int col = e & 63, k = e >> 6;
    float f = W2[(size_t)k * HID + col];
    ushort_t hi, lo;
    split_bf(f, hi, lo);
    int idx = col * 64 + (((k >> 3) ^ (col & 7)) << 3) + (k & 7);
    whi[idx] = hi;
    wlo[idx] = lo;
}

// ---------- bin edges by dst>>9; packed record = src | (localnode<<20) ----------
__global__ __launch_bounds__(256) void k_bin(const int* __restrict__ ei,
                                             int* __restrict__ bcur,
                                             uint_t* __restrict__ binned, int E) {
    __shared__ int hist[NBKT];
    __shared__ int base[NBKT];
    const int t = threadIdx.x;
    const int c0 = blockIdx.x * 4096;
    hist[t] = 0;
    __syncthreads();
#pragma unroll
    for (int i = 0; i < 16; ++i) {
        int e = c0 + i * 256 + t;
        if (e < E) atomicAdd(&hist[ei[E + e] >> 9], 1);
    }
    __syncthreads();
    {
        int h = hist[t];
        base[t] = (h > 0) ? atomicAdd(&bcur[t], h) : 0;
        hist[t] = 0;  // reuse as local rank cursor
    }
    __syncthreads();
#pragma unroll
    for (int i = 0; i < 16; ++i) {
        int e = c0 + i * 256 + t;
        if (e < E) {
            int src = ei[e];
            int dst = ei[E + e];
            int b = dst >> 9;
            int r = atomicAdd(&hist[b], 1);
            int pos = base[b] + r;
            if (pos >= BCAP) pos = BCAP - 1;  // safety clamp
            binned[(size_t)b * BCAP + pos] = (uint_t)src | ((uint_t)(dst & 511) << 20);
        }
    }
}

// ---------- csrA: per-bucket counts, dinv, local padded offsets, bucket padded sum ----
__global__ __launch_bounds__(256) void k_csrA(const uint_t* __restrict__ binned,
                                              const int* __restrict__ bcur,
                                              int* __restrict__ cnt,
                                              float* __restrict__ dinv,
                                              int* __restrict__ offl,
                                              int* __restrict__ bpad, int N) {
    __shared__ int cl[512];
    __shared__ int ps[256];
    const int b = blockIdx.x, t = threadIdx.x;
    const int nE = bcur[b];
    const uint_t* be = binned + (size_t)b * BCAP;
    cl[t] = 0;
    cl[t + 256] = 0;
    __syncthreads();
    for (int i = t; i < nE; i += 256) atomicAdd(&cl[be[i] >> 20], 1);
    __syncthreads();
    const int ca = cl[2 * t], cb = cl[2 * t + 1];
    const int p4a = (ca + 3) & ~3, p4b = (cb + 3) & ~3;
    const int p = p4a + p4b;
    ps[t] = p;
    __syncthreads();
#pragma unroll
    for (int o = 1; o < 256; o <<= 1) {
        int add = (t >= o) ? ps[t - o] : 0;
        __syncthreads();
        ps[t] += add;
        __syncthreads();
    }
    const int pbase = ps[t] - p;
    const int g0 = b * 512 + 2 * t;
    if (g0 < N) {
        cnt[g0] = ca;
        dinv[g0] = rsqrtf((float)(ca + 1));
        offl[g0] = pbase;
    }
    if (g0 + 1 < N) {
        cnt[g0 + 1] = cb;
        dinv[g0 + 1] = rsqrtf((float)(cb + 1));
        offl[g0 + 1] = pbase + p4a;
    }
    if (t == 255) bpad[b] = ps[255];
}

// ---------- scan bucket padded totals -> bases; rowstart[N] = Epad ----------
__global__ __launch_bounds__(256) void k_bktscan(const int* __restrict__ bpad,
                                                 int* __restrict__ bbase,
                                                 int* __restrict__ rowstart, int N) {
    __shared__ int s[256];
    const int t = threadIdx.x;
    const int v = bpad[t];
    s[t] = v;
    __syncthreads();
#pragma unroll
    for (int off = 1; off < 256; off <<= 1) {
        int add = (t >= off) ? s[t - off] : 0;
        __syncthreads();
        s[t] += add;
        __syncthreads();
    }
    bbase[t] = s[t] - v;
    if (t == 255) rowstart[N] = s[255];
}

// ---------- csrB: rowstart, scatter srcs, fill padding with N ----------
__global__ __launch_bounds__(256) void k_csrB(const uint_t* __restrict__ binned,
                                              const int* __restrict__ bcur,
                                              const int* __restrict__ bbase,
                                              const int* __restrict__ offl,
                                              const int* __restrict__ cnt,
                                              int* __restrict__ csr,
                                              int* __restrict__ rowstart, int N) {
    __shared__ int st[512];
    __shared__ int cur[512];
    const int b = blockIdx.x, t = threadIdx.x;
    const int nE = bcur[b];
    const int gb = bbase[b];
    const uint_t* be = binned + (size_t)b * BCAP;
    const int n0 = b * 512;
    for (int i = t; i < 512; i += 256) {
        int g = n0 + i;
        int s = (g < N) ? gb + offl[g] : 0;
        st[i] = s;
        cur[i] = s;
        if (g < N) rowstart[g] = s;
    }
    __syncthreads();
    for (int i = t; i < nE; i += 256) {
        uint_t rec = be[i];
        int ln = rec >> 20;
        int r = atomicAdd(&cur[ln], 1);
        csr[r] = (int)(rec & 0xFFFFFu);
    }
    __syncthreads();
    for (int i = t; i < 512; i += 256) {
        int g = n0 + i;
        if (g < N) {
            int c = cnt[g];
            int end = st[i] + ((c + 3) & ~3);
            for (int j = st[i] + c; j < end; ++j) csr[j] = N;  // dummy -> zero row
        }
    }
}

// ---------- GEMM1 (MFMA) + gelu + LN: u0 = dinv * LN(gelu(x @ W1 + b1)) ----------
// 512 thr = 8 waves, wave -> 16 rows x 64 cols; W hi/lo in 64KB LDS; all x preloaded.
// A-operand: single rounded bf16 (x_lo term dropped: ~2^-9 rel err, negligible vs LN).
// 2 MFMAs per (t8,ct): ahi*bhi + ahi*blo. u0 row-major [N+1][64] bf16.
__global__ __launch_bounds__(512, 4) void k_gemm1ln(const float* __restrict__ x,
                                                    const ushort_t* __restrict__ whi,
                                                    const ushort_t* __restrict__ wlo,
                                                    const float* __restrict__ b1,
                                                    const float* __restrict__ g1,
                                                    const float* __restrict__ be1,
                                                    const float* __restrict__ dinv,
                                                    ushort_t* __restrict__ u0, int N) {
    __shared__ ushort_t Wh[16384];
    __shared__ ushort_t Wl[16384];
    const int t = threadIdx.x;
    {
        const uint4* s1 = (const uint4*)whi;
        uint4* d1 = (uint4*)Wh;
        for (int i = t; i < 2048; i += 512) d1[i] = s1[i];
        const uint4* s2 = (const uint4*)wlo;
        uint4* d2 = (uint4*)Wl;
        for (int i = t; i < 2048; i += 512) d2[i] = s2[i];
    }

    const int lane = t & 63, w = t >> 6;
    const int l15 = lane & 15, lg = lane >> 4;
    const int row0 = blockIdx.x * 128 + w * 16;
    int rowc = row0 + l15;
    if (rowc > N - 1) rowc = N - 1;
    const float* xr = x + (size_t)rowc * INC + lg * 8;

    float4 ax[16];
#pragma unroll
    for (int i = 0; i < 8; ++i) {
        ax[2 * i] = *(const float4*)(xr + i * 32);
        ax[2 * i + 1] = *(const float4*)(xr + i * 32 + 4);
    }
    __syncthreads();

    float4v acc[4];
#pragma unroll
    for (int i = 0; i < 4; ++i) acc[i] = (float4v){0.f, 0.f, 0.f, 0.f};

    union U8 { short8v v; ushort_t u[8]; };

#pragma unroll
    for (int t8 = 0; t8 < 8; ++t8) {
        U8 ahi;
        {
            const float af[8] = {ax[2 * t8].x, ax[2 * t8].y, ax[2 * t8].z, ax[2 * t8].w,
                                 ax[2 * t8 + 1].x, ax[2 * t8 + 1].y, ax[2 * t8 + 1].z,
                                 ax[2 * t8 + 1].w};
#pragma unroll
            for (int j = 0; j < 8; ++j) ahi.u[j] = f2bf(af[j]);
        }
        const int kb = t8 * 4 + lg;
#pragma unroll
        for (int ct = 0; ct < 4; ++ct) {
            const int col = ct * 16 + l15;
            const int idx = col * 256 + ((kb ^ (col & 7)) << 3);
            const short8v bhi = *(const short8v*)&Wh[idx];
            const short8v blo = *(const short8v*)&Wl[idx];
            acc[ct] = __builtin_amdgcn_mfma_f32_16x16x32_bf16(ahi.v, bhi, acc[ct], 0, 0, 0);
            acc[ct] = __builtin_amdgcn_mfma_f32_16x16x32_bf16(ahi.v, blo, acc[ct], 0, 0, 0);
        }
    }

    float b1c[4], g1c[4], bec[4];
#pragma unroll
    for (int ct = 0; ct < 4; ++ct) {
        const int col = ct * 16 + l15;
        b1c[ct] = b1[col];
        g1c[ct] = g1[col];
        bec[ct] = be1[col];
    }
    float gv[4][4];
#pragma unroll
    for (int ct = 0; ct < 4; ++ct)
#pragma unroll
        for (int r = 0; r < 4; ++r) gv[ct][r] = gelu_exact(acc[ct][r] + b1c[ct]);

    float mu[4], rsv[4];
#pragma unroll
    for (int r = 0; r < 4; ++r) {
        float p = gv[0][r] + gv[1][r] + gv[2][r] + gv[3][r];
        p += __shfl_xor(p, 1, 64);
        p += __shfl_xor(p, 2, 64);
        p += __shfl_xor(p, 4, 64);
        p += __shfl_xor(p, 8, 64);
        mu[r] = p * (1.0f / 64.0f);
        float d0 = gv[0][r] - mu[r], d1 = gv[1][r] - mu[r];
        float d2 = gv[2][r] - mu[r], d3 = gv[3][r] - mu[r];
        float p2 = d0 * d0 + d1 * d1 + d2 * d2 + d3 * d3;
        p2 += __shfl_xor(p2, 1, 64);
        p2 += __shfl_xor(p2, 2, 64);
        p2 += __shfl_xor(p2, 4, 64);
        p2 += __shfl_xor(p2, 8, 64);
        rsv[r] = rsqrtf(p2 * (1.0f / 64.0f) + LN_EPS);
    }
#pragma unroll
    for (int r = 0; r < 4; ++r) {
        const int row = row0 + lg * 4 + r;
        if (row < N) {
            const float di = dinv[row];
#pragma unroll
            for (int ct = 0; ct < 4; ++ct) {
                const float ln = (gv[ct][r] - mu[r]) * rsv[r] * g1c[ct] + bec[ct];
                u0[(size_t)row * HID + ct * 16 + l15] = f2bf(di * ln);
            }
        }
    }
}

// ---------- APPNP step in u-space, deep-MLP (R10 best form, frozen) ----------
__global__ __launch_bounds__(256) void k_prop(const ushort_t* __restrict__ uin,
                                              const ushort_t* __restrict__ u0,
                                              ushort_t* __restrict__ uout,
                                              const int* __restrict__ csr,
                                              const int* __restrict__ rowstart,
                                              const float* __restrict__ dinv, int N) {
    const int t = threadIdx.x;
    const int lane = t & 63;
    const int q = lane >> 4, fl = lane & 15;
    const int node = blockIdx.x * 4 + (t >> 6);
    if (node >= N) return;
    const uint2* U = (const uint2*)uin;
    const int s0 = rowstart[node];
    const int e1 = rowstart[node + 1];
    const int r = e1 - s0;  // multiple of 4

    const uint2 ud = U[(size_t)node * 16 + fl];
    const uint2 uz = ((const uint2*)u0)[(size_t)node * 16 + fl];
    const float di = dinv[node];

    const int oa = 4 * q;       // 0,4,8,12
    const int ob = 16 + 4 * q;  // 16,20,24,28
    int4 ia = make_int4(N, N, N, N);
    int4 ib = make_int4(N, N, N, N);
    if (oa < r) ia = *(const int4*)(csr + s0 + oa);
    if (ob < r) ib = *(const int4*)(csr + s0 + ob);

    const uint2 va0 = U[(size_t)ia.x * 16 + fl];
    const uint2 va1 = U[(size_t)ia.y * 16 + fl];
    const uint2 va2 = U[(size_t)ia.z * 16 + fl];
    const uint2 va3 = U[(size_t)ia.w * 16 + fl];
    const uint2 vb0 = U[(size_t)ib.x * 16 + fl];
    const uint2 vb1 = U[(size_t)ib.y * 16 + fl];
    const uint2 vb2 = U[(size_t)ib.z * 16 + fl];
    const uint2 vb3 = U[(size_t)ib.w * 16 + fl];

    float a0 = bf_lo(va0.x) + bf_lo(va1.x) + bf_lo(va2.x) + bf_lo(va3.x)
             + bf_lo(vb0.x) + bf_lo(vb1.x) + bf_lo(vb2.x) + bf_lo(vb3.x);
    float a1 = bf_hi(va0.x) + bf_hi(va1.x) + bf_hi(va2.x) + bf_hi(va3.x)
             + bf_hi(vb0.x) + bf_hi(vb1.x) + bf_hi(vb2.x) + bf_hi(vb3.x);
    float a2 = bf_lo(va0.y) + bf_lo(va1.y) + bf_lo(va2.y) + bf_lo(va3.y)
             + bf_lo(vb0.y) + bf_lo(vb1.y) + bf_lo(vb2.y) + bf_lo(vb3.y);
    float a3 = bf_hi(va0.y) + bf_hi(va1.y) + bf_hi(va2.y) + bf_hi(va3.y)
             + bf_hi(vb0.y) + bf_hi(vb1.y) + bf_hi(vb2.y) + bf_hi(vb3.y);

    for (int e = s0 + 32; e < e1; e += 16) {
        const int ge = e + 4 * q;
        int4 id = make_int4(N, N, N, N);
        if (ge < e1) id = *(const int4*)(csr + ge);
        const uint2 v0 = U[(size_t)id.x * 16 + fl];
        const uint2 v1 = U[(size_t)id.y * 16 + fl];
        const uint2 v2 = U[(size_t)id.z * 16 + fl];
        const uint2 v3 = U[(size_t)id.w * 16 + fl];
        a0 += bf_lo(v0.x) + bf_lo(v1.x) + bf_lo(v2.x) + bf_lo(v3.x);
        a1 += bf_hi(v0.x) + bf_hi(v1.x) + bf_hi(v2.x) + bf_hi(v3.x);
        a2 += bf_lo(v0.y) + bf_lo(v1.y) + bf_lo(v2.y) + bf_lo(v3.y);
        a3 += bf_hi(v0.y) + bf_hi(v1.y) + bf_hi(v2.y) + bf_hi(v3.y);
    }

    a0 += __shfl_xor(a0, 16, 64); a0 += __shfl_xor(a0, 32, 64);
    a1 += __shfl_xor(a1, 16, 64); a1 += __shfl_xor(a1, 32, 64);
    a2 += __shfl_xor(a2, 16, 64); a2 += __shfl_xor(a2, 32, 64);
    a3 += __shfl_xor(a3, 16, 64); a3 += __shfl_xor(a3, 32, 64);
    if (lane < 16) {
        const float c = (1.0f - ALPHA) * di * di;
        const float r0 = c * (a0 + bf_lo(ud.x)) + ALPHA * bf_lo(uz.x);
        const float r1 = c * (a1 + bf_hi(ud.x)) + ALPHA * bf_hi(uz.x);
        const float r2 = c * (a2 + bf_lo(ud.y)) + ALPHA * bf_lo(uz.y);
        const float r3 = c * (a3 + bf_hi(ud.y)) + ALPHA * bf_hi(uz.y);
        uint2 o;
        o.x = (uint_t)f2bf(r0) | ((uint_t)f2bf(r1) << 16);
        o.y = (uint_t)f2bf(r2) | ((uint_t)f2bf(r3) << 16);
        ((uint2*)uout)[(size_t)node * 16 + fl] = o;
    }
}

// ---------- final (MFMA): out = LN(gelu(u/dinv)) @ W2 + b2 ----------
__global__ __launch_bounds__(256) void k_final(const ushort_t* __restrict__ u,
                                               const int* __restrict__ cnt,
                                               const float* __restrict__ g2,
                                               const float* __restrict__ be2,
                                               const ushort_t* __restrict__ w2hi,
                                               const ushort_t* __restrict__ w2lo,
                                               const float* __restrict__ b2,
                                               float* __restrict__ out, int N) {
    __shared__ ushort_t Wh[4096];
    __shared__ ushort_t Wl[4096];
    const int t = threadIdx.x;
    {
        const uint4* s1 = (const uint4*)w2hi;
        uint4* d1 = (uint4*)Wh;
        for (int i = t; i < 512; i += 256) d1[i] = s1[i];
        const uint4* s2 = (const uint4*)w2lo;
        uint4* d2 = (uint4*)Wl;
        for (int i = t; i < 512; i += 256) d2[i] = s2[i];
    }
    __syncthreads();

    const int lane = t & 63, w = t >> 6;
    const int l15 = lane & 15, lg = lane >> 4;
    const int row0 = blockIdx.x * 64 + w * 16;
    if (row0 >= N) return;
    int rowc = row0 + l15;
    if (rowc > N - 1) rowc = N - 1;

    const uint4 uva = *(const uint4*)(u + (size_t)rowc * HID + lg * 8);
    const uint4 uvb = *(const uint4*)(u + (size_t)rowc * HID + 32 + lg * 8);
    const float sc = sqrtf((float)(cnt[rowc] + 1));  // 1/dinv

    float v[16];
    {
        const uint_t ua_[4] = {uva.x, uva.y, uva.z, uva.w};
        const uint_t ub_[4] = {uvb.x, uvb.y, uvb.z, uvb.w};
#pragma unroll
        for (int j = 0; j < 4; ++j) {
            v[2 * j] = gelu_exact(bf_lo(ua_[j]) * sc);
            v[2 * j + 1] = gelu_exact(bf_hi(ua_[j]) * sc);
            v[8 + 2 * j] = gelu_exact(bf_lo(ub_[j]) * sc);
            v[8 + 2 * j + 1] = gelu_exact(bf_hi(ub_[j]) * sc);
        }
    }
    float s = 0.f;
#pragma unroll
    for (int j = 0; j < 16; ++j) s += v[j];
    s += __shfl_xor(s, 16, 64);
    s += __shfl_xor(s, 32, 64);
    const float mu = s * (1.0f / 64.0f);
    float sq = 0.f;
#pragma unroll
    for (int j = 0; j < 16; ++j) {
        v[j] -= mu;
        sq += v[j] * v[j];
    }
    sq += __shfl_xor(sq, 16, 64);
    sq += __shfl_xor(sq, 32, 64);
    const float rs = rsqrtf(sq * (1.0f / 64.0f) + LN_EPS);

    union U8 { short8v v; ushort_t u[8]; };
    U8 a0, a1;
#pragma unroll
    for (int j = 0; j < 8; ++j) {
        const int ka = lg * 8 + j;
        const int kb = 32 + lg * 8 + j;
        a0.u[j] = f2bf(v[j] * rs * g2[ka] + be2[ka]);
        a1.u[j] = f2bf(v[8 + j] * rs * g2[kb] + be2[kb]);
    }

    float4v acc[4];
#pragma unroll
    for (int i = 0; i < 4; ++i) acc[i] = (float4v){0.f, 0.f, 0.f, 0.f};
#pragma unroll
    for (int ct = 0; ct < 4; ++ct) {
        const int col = ct * 16 + l15;
        const int i0 = col * 64 + ((lg ^ (col & 7)) << 3);
        const int i1 = col * 64 + (((4 + lg) ^ (col & 7)) << 3);
        short8v b0h = *(const short8v*)&Wh[i0];
        short8v b0l = *(const short8v*)&Wl[i0];
        short8v b1h = *(const short8v*)&Wh[i1];
        short8v b1l = *(const short8v*)&Wl[i1];
        acc[ct] = __builtin_amdgcn_mfma_f32_16x16x32_bf16(a0.v, b0h, acc[ct], 0, 0, 0);
        acc[ct] = __builtin_amdgcn_mfma_f32_16x16x32_bf16(a0.v, b0l, acc[ct], 0, 0, 0);
        acc[ct] = __builtin_amdgcn_mfma_f32_16x16x32_bf16(a1.v, b1h, acc[ct], 0, 0, 0);
        acc[ct] = __builtin_amdgcn_mfma_f32_16x16x32_bf16(a1.v, b1l, acc[ct], 0, 0, 0);
    }

#pragma unroll
    for (int ct = 0; ct < 4; ++ct) {
        const float bb = b2[ct * 16 + l15];
#pragma unroll
        for (int r = 0; r < 4; ++r) {
            const int row = row0 + lg * 4 + r;
            if (row < N) out[(size_t)row * HID + ct * 16 + l15] = acc[ct][r] + bb;
        }
    }
}

extern "C" void kernel_launch(void* const* d_in, const int* in_sizes, int n_in,
                              void* d_out, int out_size, void* d_ws, size_t ws_size,
                              hipStream_t stream) {
    const float* x   = (const float*)d_in[0];
    const int*   ei  = (const int*)d_in[1];
    const float* W1  = (const float*)d_in[2];
    const float* b1  = (const float*)d_in[3];
    const float* g1  = (const float*)d_in[4];
    const float* be1 = (const float*)d_in[5];
    const float* g2  = (const float*)d_in[6];
    const float* be2 = (const float*)d_in[7];
    const float* W2  = (const float*)d_in[8];
    const float* b2  = (const float*)d_in[9];
    float* out = (float*)d_out;

    const int N = in_sizes[0] / INC;
    const int E = in_sizes[1] / 2;

    char* ws = (char*)d_ws;
    size_t o = 0;
    auto alloc = [&](size_t bytes) { size_t r = o; o += (bytes + 255) & ~(size_t)255; return r; };
    ushort_t* u0 = (ushort_t*)(ws + alloc((size_t)(N + 1) * HID * 2));
    ushort_t* ua = (ushort_t*)(ws + alloc((size_t)(N + 1) * HID * 2));
    ushort_t* ub = (ushort_t*)(ws + alloc((size_t)(N + 1) * HID * 2));
    float* dinv     = (float*)(ws + alloc((size_t)N * 4));
    int*   cnt      = (int*)(ws + alloc((size_t)N * 4));
    int*   offl     = (int*)(ws + alloc((size_t)N * 4));
    int*   rowstart = (int*)(ws + alloc((size_t)(N + 1) * 4));
    int*   bcur     = (int*)(ws + alloc(NBKT * 4));
    int*   bpad     = (int*)(ws + alloc(NBKT * 4));
    int*   bbase    = (int*)(ws + alloc(NBKT * 4));
    ushort_t* whi   = (ushort_t*)(ws + alloc(16384 * 2));
    ushort_t* wlo   = (ushort_t*)(ws + alloc(16384 * 2));
    ushort_t* w2hi  = (ushort_t*)(ws + alloc(4096 * 2));
    ushort_t* w2lo  = (ushort_t*)(ws + alloc(4096 * 2));
    uint_t* binned  = (uint_t*)(ws + alloc((size_t)NBKT * BCAP * 4));
    int*   csr      = (int*)(ws + alloc((size_t)(E + 3 * (size_t)N + 256) * 4));

    const int nbkt = (N + 511) / 512;  // 196 for N=100000

    hipMemsetAsync(bcur, 0, NBKT * 4, stream);
    hipMemsetAsync(bpad, 0, NBKT * 4, stream);
    // zero dummy row N of each u buffer (gather target for CSR padding)
    hipMemsetAsync(u0 + (size_t)N * HID, 0, HID * 2, stream);
    hipMemsetAsync(ua + (size_t)N * HID, 0, HID * 2, stream);
    hipMemsetAsync(ub + (size_t)N * HID, 0, HID * 2, stream);

    k_prepW<<<64, 256, 0, stream>>>(W1, whi, wlo);
    k_prepW2<<<16, 256, 0, stream>>>(W2, w2hi, w2lo);
    k_bin<<<(E + 4095) / 4096, 256, 0, stream>>>(ei, bcur, binned, E);
    k_csrA<<<nbkt, 256, 0, stream>>>(binned, bcur, cnt, dinv, offl, bpad, N);
    k_bktscan<<<1, 256, 0, stream>>>(bpad, bbase, rowstart, N);
    k_csrB<<<nbkt, 256, 0, stream>>>(binned, bcur, bbase, offl, cnt, csr, rowstart, N);
    k_gemm1ln<<<(N + 127) / 128, 512, 0, stream>>>(x, whi, wlo, b1, g1, be1, dinv, u0, N);

    ushort_t* bufs[2] = {ua, ub};
    const ushort_t* pin = u0;
    for (int k = 0; k < 10; ++k) {
        ushort_t* pout = bufs[k & 1];
        k_prop<<<(N + 3) / 4, 256, 0, stream>>>(pin, u0, pout, csr, rowstart, dinv, N);
        pin = pout;
    }
    k_final<<<(N + 63) / 64, 256, 0, stream>>>(pin, cnt, g2, be2, w2hi, w2lo, b2, out, N);
}

// Round 12
// 513.137 us; speedup vs baseline: 2.2807x; 1.0089x over previous
//
#include <hip/hip_runtime.h>
#include <math.h>

#define HID 64
#define INC 256
#define LN_EPS 1e-5f
#define ALPHA 0.1f
#define NBKT 256     // max buckets (N<=131072); actual = ceil(N/512)
#define BCAP 12288   // per-bucket capacity; E/N*512 = 8192 expected, +45 sigma margin

typedef unsigned short ushort_t;
typedef unsigned int uint_t;
using short8v = __attribute__((ext_vector_type(8))) short;
using float4v = __attribute__((ext_vector_type(4))) float;

__device__ __forceinline__ float gelu_exact(float x) {
    return 0.5f * x * (1.0f + erff(x * 0.70710678118654752f));
}

__device__ __forceinline__ ushort_t f2bf(float f) {
    uint_t u = __float_as_uint(f);
    return (ushort_t)((u + 0x7fffu + ((u >> 16) & 1u)) >> 16);
}
__device__ __forceinline__ float bf_lo(uint_t v) { return __uint_as_float(v << 16); }
__device__ __forceinline__ float bf_hi(uint_t v) { return __uint_as_float(v & 0xffff0000u); }

__device__ __forceinline__ void split_bf(float f, ushort_t& hi, ushort_t& lo) {
    uint_t ub = __float_as_uint(f);
    uint_t h = (ub + 0x7fffu + ((ub >> 16) & 1u)) >> 16;
    hi = (ushort_t)h;
    float fl = f - __uint_as_float(h << 16);
    uint_t lb = __float_as_uint(fl);
    lo = (ushort_t)((lb + 0x7fffu + ((lb >> 16) & 1u)) >> 16);
}

// ---------- prep: W1 [256][64] f32 -> swizzled W^T bf16 (single, rounded) [64][256] ----
__global__ __launch_bounds__(256) void k_prepW(const float* __restrict__ W1,
                                               ushort_t* __restrict__ whi) {
    int e = blockIdx.x * 256 + threadIdx.x;  // 16384 total
    int col = e & 63, k = e >> 6;
    float f = W1[(size_t)k * HID + col];
    int idx = col * 256 + (((k >> 3) ^ (col & 7)) << 3) + (k & 7);
    whi[idx] = f2bf(f);
}

// ---------- prep: W2 [64][64] f32 -> swizzled W^T bf16 hi/lo [64][64] ----------
__global__ __launch_bounds__(256) void k_prepW2(const float* __restrict__ W2,
                                                ushort_t* __restrict__ whi,
                                                ushort_t* __restrict__ wlo) {
    int e = blockIdx.x * 256 + threadIdx.x;  // 4096 total
    int col = e & 63, k = e >> 6;
    float f = W2[(size_t)k * HID + col];
    ushort_t hi, lo;
    split_bf(f, hi, lo);
    int idx = col * 64 + (((k >> 3) ^ (col & 7)) << 3) + (k & 7);
    whi[idx] = hi;
    wlo[idx] = lo;
}

// ---------- bin edges by dst>>9; packed record = src | (localnode<<20) ----------
__global__ __launch_bounds__(256) void k_bin(const int* __restrict__ ei,
                                             int* __restrict__ bcur,
                                             uint_t* __restrict__ binned, int E) {
    __shared__ int hist[NBKT];
    __shared__ int base[NBKT];
    const int t = threadIdx.x;
    const int c0 = blockIdx.x * 4096;
    hist[t] = 0;
    __syncthreads();
#pragma unroll
    for (int i = 0; i < 16; ++i) {
        int e = c0 + i * 256 + t;
        if (e < E) atomicAdd(&hist[ei[E + e] >> 9], 1);
    }
    __syncthreads();
    {
        int h = hist[t];
        base[t] = (h > 0) ? atomicAdd(&bcur[t], h) : 0;
        hist[t] = 0;  // reuse as local rank cursor
    }
    __syncthreads();
#pragma unroll
    for (int i = 0; i < 16; ++i) {
        int e = c0 + i * 256 + t;
        if (e < E) {
            int src = ei[e];
            int dst = ei[E + e];
            int b = dst >> 9;
            int r = atomicAdd(&hist[b], 1);
            int pos = base[b] + r;
            if (pos >= BCAP) pos = BCAP - 1;  // safety clamp
            binned[(size_t)b * BCAP + pos] = (uint_t)src | ((uint_t)(dst & 511) << 20);
        }
    }
}

// ---------- csrA: per-bucket counts, dinv, local padded offsets, bucket padded sum ----
__global__ __launch_bounds__(256) void k_csrA(const uint_t* __restrict__ binned,
                                              const int* __restrict__ bcur,
                                              int* __restrict__ cnt,
                                              float* __restrict__ dinv,
                                              int* __restrict__ offl,
                                              int* __restrict__ bpad, int N) {
    __shared__ int cl[512];
    __shared__ int ps[256];
    const int b = blockIdx.x, t = threadIdx.x;
    const int nE = bcur[b];
    const uint_t* be = binned + (size_t)b * BCAP;
    cl[t] = 0;
    cl[t + 256] = 0;
    __syncthreads();
    for (int i = t; i < nE; i += 256) atomicAdd(&cl[be[i] >> 20], 1);
    __syncthreads();
    const int ca = cl[2 * t], cb = cl[2 * t + 1];
    const int p4a = (ca + 3) & ~3, p4b = (cb + 3) & ~3;
    const int p = p4a + p4b;
    ps[t] = p;
    __syncthreads();
#pragma unroll
    for (int o = 1; o < 256; o <<= 1) {
        int add = (t >= o) ? ps[t - o] : 0;
        __syncthreads();
        ps[t] += add;
        __syncthreads();
    }
    const int pbase = ps[t] - p;
    const int g0 = b * 512 + 2 * t;
    if (g0 < N) {
        cnt[g0] = ca;
        dinv[g0] = rsqrtf((float)(ca + 1));
        offl[g0] = pbase;
    }
    if (g0 + 1 < N) {
        cnt[g0 + 1] = cb;
        dinv[g0 + 1] = rsqrtf((float)(cb + 1));
        offl[g0 + 1] = pbase + p4a;
    }
    if (t == 255) bpad[b] = ps[255];
}

// ---------- scan bucket padded totals -> bases; rowstart[N] = Epad ----------
__global__ __launch_bounds__(256) void k_bktscan(const int* __restrict__ bpad,
                                                 int* __restrict__ bbase,
                                                 int* __restrict__ rowstart, int N) {
    __shared__ int s[256];
    const int t = threadIdx.x;
    const int v = bpad[t];
    s[t] = v;
    __syncthreads();
#pragma unroll
    for (int off = 1; off < 256; off <<= 1) {
        int add = (t >= off) ? s[t - off] : 0;
        __syncthreads();
        s[t] += add;
        __syncthreads();
    }
    bbase[t] = s[t] - v;
    if (t == 255) rowstart[N] = s[255];
}

// ---------- csrB: rowstart, scatter srcs, fill padding with N ----------
__global__ __launch_bounds__(256) void k_csrB(const uint_t* __restrict__ binned,
                                              const int* __restrict__ bcur,
                                              const int* __restrict__ bbase,
                                              const int* __restrict__ offl,
                                              const int* __restrict__ cnt,
                                              int* __restrict__ csr,
                                              int* __restrict__ rowstart, int N) {
    __shared__ int st[512];
    __shared__ int cur[512];
    const int b = blockIdx.x, t = threadIdx.x;
    const int nE = bcur[b];
    const int gb = bbase[b];
    const uint_t* be = binned + (size_t)b * BCAP;
    const int n0 = b * 512;
    for (int i = t; i < 512; i += 256) {
        int g = n0 + i;
        int s = (g < N) ? gb + offl[g] : 0;
        st[i] = s;
        cur[i] = s;
        if (g < N) rowstart[g] = s;
    }
    __syncthreads();
    for (int i = t; i < nE; i += 256) {
        uint_t rec = be[i];
        int ln = rec >> 20;
        int r = atomicAdd(&cur[ln], 1);
        csr[r] = (int)(rec & 0xFFFFFu);
    }
    __syncthreads();
    for (int i = t; i < 512; i += 256) {
        int g = n0 + i;
        if (g < N) {
            int c = cnt[g];
            int end = st[i] + ((c + 3) & ~3);
            for (int j = st[i] + c; j < end; ++j) csr[j] = N;  // dummy -> zero row
        }
    }
}

// ---------- GEMM1 (MFMA) + gelu + LN: u0 = dinv * LN(gelu(x @ W1 + b1)) ----------
// 512 thr = 8 waves, wave -> 16 rows x 64 cols; single-bf16 W in 32KB LDS
// (4 blocks/CU -> 32 waves/CU); all 16 x-float4 preloaded. 1 MFMA per (t8,ct).
// bf16 rounding of x and W adds ~0.004 abs pre-LN (vs 0.031 bf16-prop error).
__global__ __launch_bounds__(512, 8) void k_gemm1ln(const float* __restrict__ x,
                                                    const ushort_t* __restrict__ whi,
                                                    const float* __restrict__ b1,
                                                    const float* __restrict__ g1,
                                                    const float* __restrict__ be1,
                                                    const float* __restrict__ dinv,
                                                    ushort_t* __restrict__ u0, int N) {
    __shared__ ushort_t Wh[16384];
    const int t = threadIdx.x;
    {
        const uint4* s1 = (const uint4*)whi;
        uint4* d1 = (uint4*)Wh;
        for (int i = t; i < 2048; i += 512) d1[i] = s1[i];
    }

    const int lane = t & 63, w = t >> 6;
    const int l15 = lane & 15, lg = lane >> 4;
    const int row0 = blockIdx.x * 128 + w * 16;
    int rowc = row0 + l15;
    if (rowc > N - 1) rowc = N - 1;
    const float* xr = x + (size_t)rowc * INC + lg * 8;

    float4 ax[16];
#pragma unroll
    for (int i = 0; i < 8; ++i) {
        ax[2 * i] = *(const float4*)(xr + i * 32);
        ax[2 * i + 1] = *(const float4*)(xr + i * 32 + 4);
    }
    __syncthreads();

    float4v acc[4];
#pragma unroll
    for (int i = 0; i < 4; ++i) acc[i] = (float4v){0.f, 0.f, 0.f, 0.f};

    union U8 { short8v v; ushort_t u[8]; };

#pragma unroll
    for (int t8 = 0; t8 < 8; ++t8) {
        U8 ahi;
        {
            const float af[8] = {ax[2 * t8].x, ax[2 * t8].y, ax[2 * t8].z, ax[2 * t8].w,
                                 ax[2 * t8 + 1].x, ax[2 * t8 + 1].y, ax[2 * t8 + 1].z,
                                 ax[2 * t8 + 1].w};
#pragma unroll
            for (int j = 0; j < 8; ++j) ahi.u[j] = f2bf(af[j]);
        }
        const int kb = t8 * 4 + lg;
#pragma unroll
        for (int ct = 0; ct < 4; ++ct) {
            const int col = ct * 16 + l15;
            const int idx = col * 256 + ((kb ^ (col & 7)) << 3);
            const short8v bhi = *(const short8v*)&Wh[idx];
            acc[ct] = __builtin_amdgcn_mfma_f32_16x16x32_bf16(ahi.v, bhi, acc[ct], 0, 0, 0);
        }
    }

    float b1c[4], g1c[4], bec[4];
#pragma unroll
    for (int ct = 0; ct < 4; ++ct) {
        const int col = ct * 16 + l15;
        b1c[ct] = b1[col];
        g1c[ct] = g1[col];
        bec[ct] = be1[col];
    }
    float gv[4][4];
#pragma unroll
    for (int ct = 0; ct < 4; ++ct)
#pragma unroll
        for (int r = 0; r < 4; ++r) gv[ct][r] = gelu_exact(acc[ct][r] + b1c[ct]);

    float mu[4], rsv[4];
#pragma unroll
    for (int r = 0; r < 4; ++r) {
        float p = gv[0][r] + gv[1][r] + gv[2][r] + gv[3][r];
        p += __shfl_xor(p, 1, 64);
        p += __shfl_xor(p, 2, 64);
        p += __shfl_xor(p, 4, 64);
        p += __shfl_xor(p, 8, 64);
        mu[r] = p * (1.0f / 64.0f);
        float d0 = gv[0][r] - mu[r], d1 = gv[1][r] - mu[r];
        float d2 = gv[2][r] - mu[r], d3 = gv[3][r] - mu[r];
        float p2 = d0 * d0 + d1 * d1 + d2 * d2 + d3 * d3;
        p2 += __shfl_xor(p2, 1, 64);
        p2 += __shfl_xor(p2, 2, 64);
        p2 += __shfl_xor(p2, 4, 64);
        p2 += __shfl_xor(p2, 8, 64);
        rsv[r] = rsqrtf(p2 * (1.0f / 64.0f) + LN_EPS);
    }
#pragma unroll
    for (int r = 0; r < 4; ++r) {
        const int row = row0 + lg * 4 + r;
        if (row < N) {
            const float di = dinv[row];
#pragma unroll
            for (int ct = 0; ct < 4; ++ct) {
                const float ln = (gv[ct][r] - mu[r]) * rsv[r] * g1c[ct] + bec[ct];
                u0[(size_t)row * HID + ct * 16 + l15] = f2bf(di * ln);
            }
        }
    }
}

// ---------- APPNP step in u-space, deep-MLP (R10 best form, frozen) ----------
__global__ __launch_bounds__(256) void k_prop(const ushort_t* __restrict__ uin,
                                              const ushort_t* __restrict__ u0,
                                              ushort_t* __restrict__ uout,
                                              const int* __restrict__ csr,
                                              const int* __restrict__ rowstart,
                                              const float* __restrict__ dinv, int N) {
    const int t = threadIdx.x;
    const int lane = t & 63;
    const int q = lane >> 4, fl = lane & 15;
    const int node = blockIdx.x * 4 + (t >> 6);
    if (node >= N) return;
    const uint2* U = (const uint2*)uin;
    const int s0 = rowstart[node];
    const int e1 = rowstart[node + 1];
    const int r = e1 - s0;  // multiple of 4

    const uint2 ud = U[(size_t)node * 16 + fl];
    const uint2 uz = ((const uint2*)u0)[(size_t)node * 16 + fl];
    const float di = dinv[node];

    const int oa = 4 * q;       // 0,4,8,12
    const int ob = 16 + 4 * q;  // 16,20,24,28
    int4 ia = make_int4(N, N, N, N);
    int4 ib = make_int4(N, N, N, N);
    if (oa < r) ia = *(const int4*)(csr + s0 + oa);
    if (ob < r) ib = *(const int4*)(csr + s0 + ob);

    const uint2 va0 = U[(size_t)ia.x * 16 + fl];
    const uint2 va1 = U[(size_t)ia.y * 16 + fl];
    const uint2 va2 = U[(size_t)ia.z * 16 + fl];
    const uint2 va3 = U[(size_t)ia.w * 16 + fl];
    const uint2 vb0 = U[(size_t)ib.x * 16 + fl];
    const uint2 vb1 = U[(size_t)ib.y * 16 + fl];
    const uint2 vb2 = U[(size_t)ib.z * 16 + fl];
    const uint2 vb3 = U[(size_t)ib.w * 16 + fl];

    float a0 = bf_lo(va0.x) + bf_lo(va1.x) + bf_lo(va2.x) + bf_lo(va3.x)
             + bf_lo(vb0.x) + bf_lo(vb1.x) + bf_lo(vb2.x) + bf_lo(vb3.x);
    float a1 = bf_hi(va0.x) + bf_hi(va1.x) + bf_hi(va2.x) + bf_hi(va3.x)
             + bf_hi(vb0.x) + bf_hi(vb1.x) + bf_hi(vb2.x) + bf_hi(vb3.x);
    float a2 = bf_lo(va0.y) + bf_lo(va1.y) + bf_lo(va2.y) + bf_lo(va3.y)
             + bf_lo(vb0.y) + bf_lo(vb1.y) + bf_lo(vb2.y) + bf_lo(vb3.y);
    float a3 = bf_hi(va0.y) + bf_hi(va1.y) + bf_hi(va2.y) + bf_hi(va3.y)
             + bf_hi(vb0.y) + bf_hi(vb1.y) + bf_hi(vb2.y) + bf_hi(vb3.y);

    for (int e = s0 + 32; e < e1; e += 16) {
        const int ge = e + 4 * q;
        int4 id = make_int4(N, N, N, N);
        if (ge < e1) id = *(const int4*)(csr + ge);
        const uint2 v0 = U[(size_t)id.x * 16 + fl];
        const uint2 v1 = U[(size_t)id.y * 16 + fl];
        const uint2 v2 = U[(size_t)id.z * 16 + fl];
        const uint2 v3 = U[(size_t)id.w * 16 + fl];
        a0 += bf_lo(v0.x) + bf_lo(v1.x) + bf_lo(v2.x) + bf_lo(v3.x);
        a1 += bf_hi(v0.x) + bf_hi(v1.x) + bf_hi(v2.x) + bf_hi(v3.x);
        a2 += bf_lo(v0.y) + bf_lo(v1.y) + bf_lo(v2.y) + bf_lo(v3.y);
        a3 += bf_hi(v0.y) + bf_hi(v1.y) + bf_hi(v2.y) + bf_hi(v3.y);
    }

    a0 += __shfl_xor(a0, 16, 64); a0 += __shfl_xor(a0, 32, 64);
    a1 += __shfl_xor(a1, 16, 64); a1 += __shfl_xor(a1, 32, 64);
    a2 += __shfl_xor(a2, 16, 64); a2 += __shfl_xor(a2, 32, 64);
    a3 += __shfl_xor(a3, 16, 64); a3 += __shfl_xor(a3, 32, 64);
    if (lane < 16) {
        const float c = (1.0f - ALPHA) * di * di;
        const float r0 = c * (a0 + bf_lo(ud.x)) + ALPHA * bf_lo(uz.x);
        const float r1 = c * (a1 + bf_hi(ud.x)) + ALPHA * bf_hi(uz.x);
        const float r2 = c * (a2 + bf_lo(ud.y)) + ALPHA * bf_lo(uz.y);
        const float r3 = c * (a3 + bf_hi(ud.y)) + ALPHA * bf_hi(uz.y);
        uint2 o;
        o.x = (uint_t)f2bf(r0) | ((uint_t)f2bf(r1) << 16);
        o.y = (uint_t)f2bf(r2) | ((uint_t)f2bf(r3) << 16);
        ((uint2*)uout)[(size_t)node * 16 + fl] = o;
    }
}

// ---------- final (MFMA): out = LN(gelu(u/dinv)) @ W2 + b2 ----------
__global__ __launch_bounds__(256) void k_final(const ushort_t* __restrict__ u,
                                               const int* __restrict__ cnt,
                                               const float* __restrict__ g2,
                                               const float* __restrict__ be2,
                                               const ushort_t* __restrict__ w2hi,
                                               const ushort_t* __restrict__ w2lo,
                                               const float* __restrict__ b2,
                                               float* __restrict__ out, int N) {
    __shared__ ushort_t Wh[4096];
    __shared__ ushort_t Wl[4096];
    const int t = threadIdx.x;
    {
        const uint4* s1 = (const uint4*)w2hi;
        uint4* d1 = (uint4*)Wh;
        for (int i = t; i < 512; i += 256) d1[i] = s1[i];
        const uint4* s2 = (const uint4*)w2lo;
        uint4* d2 = (uint4*)Wl;
        for (int i = t; i < 512; i += 256) d2[i] = s2[i];
    }
    __syncthreads();

    const int lane = t & 63, w = t >> 6;
    const int l15 = lane & 15, lg = lane >> 4;
    const int row0 = blockIdx.x * 64 + w * 16;
    if (row0 >= N) return;
    int rowc = row0 + l15;
    if (rowc > N - 1) rowc = N - 1;

    const uint4 uva = *(const uint4*)(u + (size_t)rowc * HID + lg * 8);
    const uint4 uvb = *(const uint4*)(u + (size_t)rowc * HID + 32 + lg * 8);
    const float sc = sqrtf((float)(cnt[rowc] + 1));  // 1/dinv

    float v[16];
    {
        const uint_t ua_[4] = {uva.x, uva.y, uva.z, uva.w};
        const uint_t ub_[4] = {uvb.x, uvb.y, uvb.z, uvb.w};
#pragma unroll
        for (int j = 0; j < 4; ++j) {
            v[2 * j] = gelu_exact(bf_lo(ua_[j]) * sc);
            v[2 * j + 1] = gelu_exact(bf_hi(ua_[j]) * sc);
            v[8 + 2 * j] = gelu_exact(bf_lo(ub_[j]) * sc);
            v[8 + 2 * j + 1] = gelu_exact(bf_hi(ub_[j]) * sc);
        }
    }
    float s = 0.f;
#pragma unroll
    for (int j = 0; j < 16; ++j) s += v[j];
    s += __shfl_xor(s, 16, 64);
    s += __shfl_xor(s, 32, 64);
    const float mu = s * (1.0f / 64.0f);
    float sq = 0.f;
#pragma unroll
    for (int j = 0; j < 16; ++j) {
        v[j] -= mu;
        sq += v[j] * v[j];
    }
    sq += __shfl_xor(sq, 16, 64);
    sq += __shfl_xor(sq, 32, 64);
    const float rs = rsqrtf(sq * (1.0f / 64.0f) + LN_EPS);

    union U8 { short8v v; ushort_t u[8]; };
    U8 a0, a1;
#pragma unroll
    for (int j = 0; j < 8; ++j) {
        const int ka = lg * 8 + j;
        const int kb = 32 + lg * 8 + j;
        a0.u[j] = f2bf(v[j] * rs * g2[ka] + be2[ka]);
        a1.u[j] = f2bf(v[8 + j] * rs * g2[kb] + be2[kb]);
    }

    float4v acc[4];
#pragma unroll
    for (int i = 0; i < 4; ++i) acc[i] = (float4v){0.f, 0.f, 0.f, 0.f};
#pragma unroll
    for (int ct = 0; ct < 4; ++ct) {
        const int col = ct * 16 + l15;
        const int i0 = col * 64 + ((lg ^ (col & 7)) << 3);
        const int i1 = col * 64 + (((4 + lg) ^ (col & 7)) << 3);
        short8v b0h = *(const short8v*)&Wh[i0];
        short8v b0l = *(const short8v*)&Wl[i0];
        short8v b1h = *(const short8v*)&Wh[i1];
        short8v b1l = *(const short8v*)&Wl[i1];
        acc[ct] = __builtin_amdgcn_mfma_f32_16x16x32_bf16(a0.v, b0h, acc[ct], 0, 0, 0);
        acc[ct] = __builtin_amdgcn_mfma_f32_16x16x32_bf16(a0.v, b0l, acc[ct], 0, 0, 0);
        acc[ct] = __builtin_amdgcn_mfma_f32_16x16x32_bf16(a1.v, b1h, acc[ct], 0, 0, 0);
        acc[ct] = __builtin_amdgcn_mfma_f32_16x16x32_bf16(a1.v, b1l, acc[ct], 0, 0, 0);
    }

#pragma unroll
    for (int ct = 0; ct < 4; ++ct) {
        const float bb = b2[ct * 16 + l15];
#pragma unroll
        for (int r = 0; r < 4; ++r) {
            const int row = row0 + lg * 4 + r;
            if (row < N) out[(size_t)row * HID + ct * 16 + l15] = acc[ct][r] + bb;
        }
    }
}

extern "C" void kernel_launch(void* const* d_in, const int* in_sizes, int n_in,
                              void* d_out, int out_size, void* d_ws, size_t ws_size,
                              hipStream_t stream) {
    const float* x   = (const float*)d_in[0];
    const int*   ei  = (const int*)d_in[1];
    const float* W1  = (const float*)d_in[2];
    const float* b1  = (const float*)d_in[3];
    const float* g1  = (const float*)d_in[4];
    const float* be1 = (const float*)d_in[5];
    const float* g2  = (const float*)d_in[6];
    const float* be2 = (const float*)d_in[7];
    const float* W2  = (const float*)d_in[8];
    const float* b2  = (const float*)d_in[9];
    float* out = (float*)d_out;

    const int N = in_sizes[0] / INC;
    const int E = in_sizes[1] / 2;

    char* ws = (char*)d_ws;
    size_t o = 0;
    auto alloc = [&](size_t bytes) { size_t r = o; o += (bytes + 255) & ~(size_t)255; return r; };
    ushort_t* u0 = (ushort_t*)(ws + alloc((size_t)(N + 1) * HID * 2));
    ushort_t* ua = (ushort_t*)(ws + alloc((size_t)(N + 1) * HID * 2));
    ushort_t* ub = (ushort_t*)(ws + alloc((size_t)(N + 1) * HID * 2));
    float* dinv     = (float*)(ws + alloc((size_t)N * 4));
    int*   cnt      = (int*)(ws + alloc((size_t)N * 4));
    int*   offl     = (int*)(ws + alloc((size_t)N * 4));
    int*   rowstart = (int*)(ws + alloc((size_t)(N + 1) * 4));
    int*   bcur     = (int*)(ws + alloc(NBKT * 4));
    int*   bpad     = (int*)(ws + alloc(NBKT * 4));
    int*   bbase    = (int*)(ws + alloc(NBKT * 4));
    ushort_t* whi   = (ushort_t*)(ws + alloc(16384 * 2));
    ushort_t* w2hi  = (ushort_t*)(ws + alloc(4096 * 2));
    ushort_t* w2lo  = (ushort_t*)(ws + alloc(4096 * 2));
    uint_t* binned  = (uint_t*)(ws + alloc((size_t)NBKT * BCAP * 4));
    int*   csr      = (int*)(ws + alloc((size_t)(E + 3 * (size_t)N + 256) * 4));

    const int nbkt = (N + 511) / 512;  // 196 for N=100000

    hipMemsetAsync(bcur, 0, NBKT * 4, stream);
    hipMemsetAsync(bpad, 0, NBKT * 4, stream);
    // zero dummy row N of each u buffer (gather target for CSR padding)
    hipMemsetAsync(u0 + (size_t)N * HID, 0, HID * 2, stream);
    hipMemsetAsync(ua + (size_t)N * HID, 0, HID * 2, stream);
    hipMemsetAsync(ub + (size_t)N * HID, 0, HID * 2, stream);

    k_prepW<<<64, 256, 0, stream>>>(W1, whi);
    k_prepW2<<<16, 256, 0, stream>>>(W2, w2hi, w2lo);
    k_bin<<<(E + 4095) / 4096, 256, 0, stream>>>(ei, bcur, binned, E);
    k_csrA<<<nbkt, 256, 0, stream>>>(binned, bcur, cnt, dinv, offl, bpad, N);
    k_bktscan<<<1, 256, 0, stream>>>(bpad, bbase, rowstart, N);
    k_csrB<<<nbkt, 256, 0, stream>>>(binned, bcur, bbase, offl, cnt, csr, rowstart, N);
    k_gemm1ln<<<(N + 127) / 128, 512, 0, stream>>>(x, whi, b1, g1, be1, dinv, u0, N);

    ushort_t* bufs[2] = {ua, ub};
    const ushort_t* pin = u0;
    for (int k = 0; k < 10; ++k) {
        ushort_t* pout = bufs[k & 1];
        k_prop<<<(N + 3) / 4, 256, 0, stream>>>(pin, u0, pout, csr, rowstart, dinv, N);
        pin = pout;
    }
    k_final<<<(N + 63) / 64, 256, 0, stream>>>(pin, cnt, g2, be2, w2hi, w2lo, b2, out, N);
}